// Round 8
// baseline (489.207 us; speedup 1.0000x reference)
//
#include <hip/hip_runtime.h>

// Block_58394375356873: HomoAttention transformer block, MI355X gfx950.
// I/O dtype: float32 (per reference). Internal GEMM compute: bf16 MFMA.
// M = B*N = 64*196 = 12544.
//
// R8: R4 config (best total) with ONE change in gemm8p: LINEAR staging source
// (g0 = tid&7, no XOR) + un-swizzled fragment reads. Cross-round ledger shows
// a ~9-14 B/cyc/CU staging-drain invariant binding every schedule/occupancy
// variant, while m97 (linear source) sustained ~54 B/cyc/CU through the same
// global_load_lds. Hypothesis: the XOR-permuted per-lane source defeats the
// DMA coalescer's monotonic fast path (4x). Accept the resulting LDS read
// bank conflicts (m97 ran 874 TF with 1.7e7 of them).

#define BATCH 64
#define SEQ   196
#define CH    768
#define NHEAD 12
#define HDIM  64
#define TOPK  16
#define HID   3072
#define MROWS 12544
#define MHALF 6272
#define SCALE_F 0.125f  // 64^-0.5
#define NEGBIG -3e38f

typedef __bf16 bf16x8 __attribute__((ext_vector_type(8)));
typedef float  f32x4  __attribute__((ext_vector_type(4)));

__device__ __forceinline__ unsigned short f2b(float f) {
    union { float f; unsigned int i; } c; c.f = f;
    unsigned int u = c.i;
    return (unsigned short)((u + 0x7fffu + ((u >> 16) & 1u)) >> 16); // RNE
}
__device__ __forceinline__ float b2f(unsigned short u) {
    union { unsigned int i; float f; } c; c.i = ((unsigned int)u) << 16; return c.f;
}

// tanh-form GELU, |err vs exact erf-GELU| < 4e-4, ~10 VALU ops.
__device__ __forceinline__ float gelu_f(float v) {
    float u = v * (0.7978845608f + 0.0356774081f * v * v);
    float e = __expf(2.0f * u);
    float th = 1.0f - 2.0f / (e + 1.0f);
    return 0.5f * v * (1.0f + th);
}

// async global->LDS, 16B per lane. LDS base must be wave-uniform; HW adds lane*16.
__device__ __forceinline__ void async16(const unsigned short* g, unsigned short* l) {
    __builtin_amdgcn_global_load_lds(
        (const __attribute__((address_space(1))) unsigned int*)(g),
        (__attribute__((address_space(3))) unsigned int*)(l), 16, 0, 0);
}

// ---------------- all-weights f32 -> bf16, one dispatch ----------------
__global__ __launch_bounds__(256) void f2b4_k(const float* __restrict__ s0, unsigned short* __restrict__ d0, int n0,
                                              const float* __restrict__ s1, unsigned short* __restrict__ d1, int n1,
                                              const float* __restrict__ s2, unsigned short* __restrict__ d2, int n2,
                                              const float* __restrict__ s3, unsigned short* __restrict__ d3, int n3)
{
    int idx = (blockIdx.x * 256 + threadIdx.x) * 4;
    const float* s; unsigned short* d; int n;
    if (idx < n0) { s = s0; d = d0; n = n0; }
    else {
        idx -= n0;
        if (idx < n1) { s = s1; d = d1; n = n1; }
        else {
            idx -= n1;
            if (idx < n2) { s = s2; d = d2; n = n2; }
            else { idx -= n2; s = s3; d = d3; n = n3; }
        }
    }
    if (idx < n) {
        float4 v = *(const float4*)(s + idx);
        ushort4 o;
        o.x = f2b(v.x); o.y = f2b(v.y); o.z = f2b(v.z); o.w = f2b(v.w);
        *(ushort4*)(d + idx) = o;
    }
}

// ---------------- LayerNorm: f32|bf16 in -> bf16 out, one block per row ----------------
template<bool INF32>
__global__ __launch_bounds__(256) void ln_k(const void* __restrict__ xin,
                                            const float* __restrict__ gw,
                                            const float* __restrict__ bw,
                                            unsigned short* __restrict__ out)
{
    const int row = blockIdx.x;
    const int tid = threadIdx.x;
    float v0, v1, v2;
    if constexpr (INF32) {
        const float* xr = (const float*)xin + (size_t)row * CH;
        v0 = xr[tid]; v1 = xr[tid + 256]; v2 = xr[tid + 512];
    } else {
        const unsigned short* xr = (const unsigned short*)xin + (size_t)row * CH;
        v0 = b2f(xr[tid]); v1 = b2f(xr[tid + 256]); v2 = b2f(xr[tid + 512]);
    }
    float s  = v0 + v1 + v2;
    float sq = v0*v0 + v1*v1 + v2*v2;
#pragma unroll
    for (int off = 32; off > 0; off >>= 1) {
        s  += __shfl_down(s, off, 64);
        sq += __shfl_down(sq, off, 64);
    }
    __shared__ __align__(16) float red[8];
    if ((tid & 63) == 0) { red[(tid >> 6) * 2] = s; red[(tid >> 6) * 2 + 1] = sq; }
    __syncthreads();
    s  = red[0] + red[2] + red[4] + red[6];
    sq = red[1] + red[3] + red[5] + red[7];
    float mu  = s * (1.0f / CH);
    float var = sq * (1.0f / CH) - mu * mu;
    float rs  = rsqrtf(var + 1e-5f);
    unsigned short* orow = out + (size_t)row * CH;
    orow[tid]       = f2b((v0 - mu) * rs * gw[tid]       + bw[tid]);
    orow[tid + 256] = f2b((v1 - mu) * rs * gw[tid + 256] + bw[tid + 256]);
    orow[tid + 512] = f2b((v2 - mu) * rs * gw[tid + 512] + bw[tid + 512]);
}

// ---------------- NT GEMM (legacy 2-barrier): C = A @ W^T (+bias)(+gelu)(+resid) ----
// Kept for attn-proj (K=192) and halved fallback paths (M=6272 not /256).
template<int TM, int TN, bool BIAS, int RES, bool GELU, bool OUTF>
__global__ __launch_bounds__(256, 4)
void gemm_bt(const unsigned short* __restrict__ A,
             const unsigned short* __restrict__ Bw,
             const float* __restrict__ bias,
             const void* __restrict__ resid,
             void* __restrict__ Cout,
             int M, int N, int K)
{
    constexpr int WROWS = (TM == 128) ? 2 : 1;
    constexpr int WCOLS = 4 / WROWS;
    constexpr int JF = TN / (16 * WCOLS);           // frag cols per wave
    __shared__ __align__(16) unsigned short As[2][TM * 32];
    __shared__ __align__(16) unsigned short Bs[2][TN * 32];
    const int tid  = threadIdx.x;
    const int w    = tid >> 6;
    const int lane = tid & 63;

    const int gridN = gridDim.x, gridM = gridDim.y;
    const int lid = blockIdx.y * gridN + blockIdx.x;
    const int SG = 8 * gridN;
    const int sg = lid / SG, r = lid % SG;
    const int remM = gridM - sg * 8;
    int mloc, nloc;
    if (remM >= 8) { mloc = sg * 8 + (r & 7); nloc = r >> 3; }
    else           { mloc = sg * 8 + r % remM; nloc = r / remM; }
    const int tileM = mloc * TM;
    const int tileN = nloc * TN;

    const int wm = (w / WCOLS) * 64;                // TM=64 -> 0
    const int wn = (w % WCOLS) * (JF * 16);
    const int q   = lane >> 4;
    const int l16 = lane & 15;
    const int csw = (q ^ (l16 & 3)) * 8;            // swizzled chunk offset for frag reads

    f32x4 acc[4][JF];
#pragma unroll
    for (int i = 0; i < 4; ++i)
#pragma unroll
        for (int j = 0; j < JF; ++j) acc[i][j] = (f32x4){0.f, 0.f, 0.f, 0.f};

    const int r0 = tid >> 2;
    const int g0 = ((tid & 3) ^ (r0 & 3)) * 8;

    const unsigned short* pB[TN / 64];
    const unsigned short* pA[TM / 64];
#pragma unroll
    for (int c = 0; c < TN / 64; ++c) pB[c] = Bw + (size_t)(tileN + r0 + c * 64) * K + g0;
#pragma unroll
    for (int c = 0; c < TM / 64; ++c) pA[c] = A + (size_t)(tileM + r0 + c * 64) * K + g0;

    auto stage = [&](int buf) {
#pragma unroll
        for (int c = 0; c < TN / 64; ++c) {
            async16(pB[c], &Bs[buf][(size_t)(c * 256 + w * 64) * 8]);
            pB[c] += 32;
        }
#pragma unroll
        for (int c = 0; c < TM / 64; ++c) {
            async16(pA[c], &As[buf][(size_t)(c * 256 + w * 64) * 8]);
            pA[c] += 32;
        }
    };

    const int kIters = K >> 5;
    stage(0);
    int cur = 0;
    for (int kt = 0; kt < kIters; ++kt) {
        __syncthreads();
        if (kt + 1 < kIters) stage(cur ^ 1);
        bf16x8 af[4], bfr[JF];
#pragma unroll
        for (int i = 0; i < 4; ++i)
            af[i] = *(const bf16x8*)&As[cur][(wm + i * 16 + l16) * 32 + csw];
#pragma unroll
        for (int j = 0; j < JF; ++j)
            bfr[j] = *(const bf16x8*)&Bs[cur][(wn + j * 16 + l16) * 32 + csw];
#pragma unroll
        for (int i = 0; i < 4; ++i)
#pragma unroll
            for (int j = 0; j < JF; ++j)
                acc[i][j] = __builtin_amdgcn_mfma_f32_16x16x32_bf16(af[i], bfr[j], acc[i][j], 0, 0, 0);
        cur ^= 1;
    }

#pragma unroll
    for (int i = 0; i < 4; ++i) {
#pragma unroll
        for (int r2 = 0; r2 < 4; ++r2) {
            int row = tileM + wm + i * 16 + q * 4 + r2;
#pragma unroll
            for (int j = 0; j < JF; ++j) {
                int col = tileN + wn + j * 16 + l16;
                float v = acc[i][j][r2];
                if (BIAS) v += bias[col];
                if (GELU) v = gelu_f(v);
                if (RES == 1) v += ((const float*)resid)[(size_t)row * N + col];
                if (RES == 2) v += b2f(((const unsigned short*)resid)[(size_t)row * N + col]);
                if (OUTF) ((float*)Cout)[(size_t)row * N + col] = v;
                else      ((unsigned short*)Cout)[(size_t)row * N + col] = f2b(v);
            }
        }
    }
}

// ---------------- Persistent 4-phase 256x256 NT GEMM (R4 ring, linear staging) --------
// C[M,N] = A[M,KC] @ W[N,KC]^T (+bias)(+gelu)(+resid). M,N % 256 == 0,
// KC % 128 == 0 (T even). 512 threads = 8 waves (2M x 4N).
// R8: source addresses LINEAR (monotonic lane->address, DMA fast path);
// LDS rows linear; fragment reads un-swizzled (bank conflicts accepted).
template<int KC, bool BIAS, int RES, bool GELU, bool OUTF>
__global__ __launch_bounds__(512, 2)
void gemm8p(const unsigned short* __restrict__ A,
            const unsigned short* __restrict__ Bw,
            const float* __restrict__ bias,
            const void* __restrict__ resid,
            void* __restrict__ Cout,
            int M, int N)
{
    constexpr int T = KC / 64;
    static_assert((T & 1) == 0, "T must be even for persistent parity");
    __shared__ __align__(16) unsigned short As[2][256 * 64];
    __shared__ __align__(16) unsigned short Bs[2][256 * 64];
    const int tid  = threadIdx.x;
    const int w    = tid >> 6;
    const int lane = tid & 63;
    const int q    = lane >> 4;
    const int l16  = lane & 15;

    const int gridN = N >> 8, gridM = M >> 8;
    const int nt = gridN * gridM;
    const int P = gridDim.x;

    // XCD-locality remap (t%8 class preserved across a block's tiles).
    auto tileOf = [&](int lid2, int& tm, int& tn) {
        const int SG = 8 * gridN;
        const int sg = lid2 / SG, rr2 = lid2 % SG;
        const int remM = gridM - sg * 8;
        int mloc, nloc;
        if (remM >= 8) { mloc = sg * 8 + (rr2 & 7); nloc = rr2 >> 3; }
        else           { mloc = sg * 8 + rr2 % remM; nloc = rr2 / remM; }
        tm = mloc * 256; tn = nloc * 256;
    };

    const int wm = (w >> 2) * 128;   // wave row offset (2 rows of waves)
    const int wn = (w & 3) * 64;     // wave col offset (4 cols of waves)

    // staging (LINEAR): per 64-row DMA round, thread t covers row r0 = t>>3,
    // chunk g0 = t&7 -> LDS address == global layout, monotonic per lane.
    const int r0 = tid >> 3;
    const int g0 = tid & 7;
    const int rB = r0 + (r0 & 32);            // B round rows: {0..31, 64..95}

    const int arow = wm + l16;
    const int brow = wn + l16;

    for (int t = (int)blockIdx.x; t < nt; t += P) {
        int tileM, tileN;
        tileOf(t, tileM, tileN);
        const bool hasNext = (t + P) < nt;
        int tileM2 = tileM, tileN2 = tileN;
        if (hasNext) tileOf(t + P, tileM2, tileN2);

        const unsigned short* pA0  = A  + (size_t)(tileM  + r0) * KC + g0 * 8;
        const unsigned short* pB0  = Bw + (size_t)(tileN  + rB) * KC + g0 * 8;
        const unsigned short* pA0n = A  + (size_t)(tileM2 + r0) * KC + g0 * 8;
        const unsigned short* pB0n = Bw + (size_t)(tileN2 + rB) * KC + g0 * 8;

        // A quarter j: LDS rows {j*64..+63} u {128+j*64..+63}; v may be T (=next tile k0)
        auto stageA = [&](int v, int j) {
            const unsigned short* base = (v == T) ? pA0n : pA0;
            const int vv = (v == T) ? 0 : v;
            const unsigned short* s = base + (size_t)(j * 64) * KC + vv * 64;
            unsigned short* d = As[vv & 1] + j * 4096 + w * 512;
            async16(s, d);
            async16(s + (size_t)128 * KC, d + 8192);
        };
        // B quarter j: LDS rows (bit5==j)
        auto stageB = [&](int v, int j) {
            const unsigned short* base = (v == T) ? pB0n : pB0;
            const int vv = (v == T) ? 0 : v;
            const unsigned short* s = base + (size_t)(j * 32) * KC + vv * 64;
            unsigned short* d = Bs[vv & 1] + j * 2048 + (w * 8 + ((w & 4) << 3)) * 64;
            async16(s, d);
            async16(s + (size_t)128 * KC, d + 8192);
        };

        f32x4 acc[8][4];
#pragma unroll
        for (int i = 0; i < 8; ++i)
#pragma unroll
            for (int jn = 0; jn < 4; ++jn) acc[i][jn] = (f32x4){0.f, 0.f, 0.f, 0.f};

        if (t == (int)blockIdx.x) {
            // prologue (first tile only): A_P0,B_Q0 landed; B_Q1,A_P1 fly.
            stageA(0, 0); stageB(0, 0); stageB(0, 1); stageA(0, 1);
            asm volatile("s_waitcnt vmcnt(4)" ::: "memory");
            __builtin_amdgcn_s_barrier();
            asm volatile("" ::: "memory");
        }

#pragma unroll 2
        for (int u = 0; u < T; ++u) {
            const unsigned short* Ab = As[u & 1];
            const unsigned short* Bb = Bs[u & 1];
            const bool more = (u + 1 < T) || hasNext;
            bf16x8 af[4][2], b0[2][2], b1[2][2];

            // ---------- ph0: reads A_P0 + B_Q0; stage A_P0(u+1); MFMA (m0,n0) ----------
#pragma unroll
            for (int m = 0; m < 4; ++m)
#pragma unroll
                for (int kk = 0; kk < 2; ++kk)
                    af[m][kk] = *(const bf16x8*)&Ab[(arow + m * 16) * 64 + (((kk << 2) | q) << 3)];
#pragma unroll
            for (int n = 0; n < 2; ++n)
#pragma unroll
                for (int kk = 0; kk < 2; ++kk)
                    b0[n][kk] = *(const bf16x8*)&Bb[(brow + n * 16) * 64 + (((kk << 2) | q) << 3)];
            if (more) stageA(u + 1, 0);
            __builtin_amdgcn_s_setprio(1);
#pragma unroll
            for (int kk = 0; kk < 2; ++kk)
#pragma unroll
                for (int m = 0; m < 4; ++m)
#pragma unroll
                    for (int n = 0; n < 2; ++n)
                        acc[m][n] = __builtin_amdgcn_mfma_f32_16x16x32_bf16(af[m][kk], b0[n][kk], acc[m][n], 0, 0, 0);
            __builtin_amdgcn_s_setprio(0);

            // ---------- ph1: wait B_Q1(u); reads b1; stage B_Q0(u+1); MFMA (m0,n1) ----------
            if (more) asm volatile("s_waitcnt vmcnt(4)" ::: "memory");
            else      asm volatile("s_waitcnt vmcnt(2)" ::: "memory");
            __builtin_amdgcn_s_barrier();
            asm volatile("" ::: "memory");
#pragma unroll
            for (int n = 0; n < 2; ++n)
#pragma unroll
                for (int kk = 0; kk < 2; ++kk)
                    b1[n][kk] = *(const bf16x8*)&Bb[(brow + 32 + n * 16) * 64 + (((kk << 2) | q) << 3)];
            if (more) stageB(u + 1, 0);
            __builtin_amdgcn_s_setprio(1);
#pragma unroll
            for (int kk = 0; kk < 2; ++kk)
#pragma unroll
                for (int m = 0; m < 4; ++m)
#pragma unroll
                    for (int n = 0; n < 2; ++n)
                        acc[m][2 + n] = __builtin_amdgcn_mfma_f32_16x16x32_bf16(af[m][kk], b1[n][kk], acc[m][2 + n], 0, 0, 0);
            __builtin_amdgcn_s_setprio(0);

            // ---------- ph2: wait A_P1(u); reads af (upper); stage B_Q1(u+1); MFMA (m1,n1) ----------
            if (more) asm volatile("s_waitcnt vmcnt(4)" ::: "memory");
            else      asm volatile("s_waitcnt vmcnt(0)" ::: "memory");
            __builtin_amdgcn_s_barrier();
            asm volatile("" ::: "memory");
#pragma unroll
            for (int m = 0; m < 4; ++m)
#pragma unroll
                for (int kk = 0; kk < 2; ++kk)
                    af[m][kk] = *(const bf16x8*)&Ab[(arow + 64 + m * 16) * 64 + (((kk << 2) | q) << 3)];
            if (more) stageB(u + 1, 1);
            __builtin_amdgcn_s_setprio(1);
#pragma unroll
            for (int kk = 0; kk < 2; ++kk)
#pragma unroll
                for (int m = 0; m < 4; ++m)
#pragma unroll
                    for (int n = 0; n < 2; ++n)
                        acc[4 + m][2 + n] = __builtin_amdgcn_mfma_f32_16x16x32_bf16(af[m][kk], b1[n][kk], acc[4 + m][2 + n], 0, 0, 0);
            __builtin_amdgcn_s_setprio(0);

            // ---------- ph3: stage A_P1(u+1); boundary wait; MFMA (m1,n0) ----------
            if (more) {
                stageA(u + 1, 1);
                asm volatile("s_waitcnt vmcnt(4)" ::: "memory");  // A_P0,B_Q0 of u+1 landed
                __builtin_amdgcn_s_barrier();
                asm volatile("" ::: "memory");
            }
            __builtin_amdgcn_s_setprio(1);
#pragma unroll
            for (int kk = 0; kk < 2; ++kk)
#pragma unroll
                for (int m = 0; m < 4; ++m)
#pragma unroll
                    for (int n = 0; n < 2; ++n)
                        acc[4 + m][n] = __builtin_amdgcn_mfma_f32_16x16x32_bf16(af[m][kk], b0[n][kk], acc[4 + m][n], 0, 0, 0);
            __builtin_amdgcn_s_setprio(0);
        }

        // ---------------- coalesced epilogue (slab in buf1; DMA targets buf0) ------
        __syncthreads();   // all waves done with buf1 ds_reads; buf1 -> scratch

        float bshift[2][2];
        if (BIAS) {
#pragma unroll
            for (int nh = 0; nh < 2; ++nh)
#pragma unroll
                for (int n = 0; n < 2; ++n)
                    bshift[nh][n] = bias[tileN + wn + nh * 32 + n * 16 + l16];
        }

        if constexpr (!OUTF) {
            unsigned short* slab = &As[1][0] + (size_t)w * 1152;   // 16 x 72 bf16
            unsigned short* co = (unsigned short*)Cout;
#pragma unroll
            for (int mh = 0; mh < 2; ++mh)
#pragma unroll
                for (int m = 0; m < 4; ++m) {
#pragma unroll
                    for (int nh = 0; nh < 2; ++nh)
#pragma unroll
                        for (int n = 0; n < 2; ++n)
#pragma unroll
                            for (int r2 = 0; r2 < 4; ++r2) {
                                float v = acc[mh * 4 + m][nh * 2 + n][r2];
                                if (BIAS) v += bshift[nh][n];
                                if (GELU) v = gelu_f(v);
                                slab[(q * 4 + r2) * 72 + nh * 32 + n * 16 + l16] = f2b(v);
                            }
#pragma unroll
                    for (int h = 0; h < 2; ++h) {
                        const int lr = h * 8 + (lane >> 3);
                        const int grow = tileM + wm + mh * 64 + m * 16 + lr;
                        const int gcol = tileN + wn + (lane & 7) * 8;
                        uint4 pk = *(const uint4*)&slab[lr * 72 + (lane & 7) * 8];
                        if (RES != 0) {
                            unsigned short* ps = (unsigned short*)&pk;
#pragma unroll
                            for (int j = 0; j < 8; ++j) {
                                float v = b2f(ps[j]);
                                if (RES == 1) v += ((const float*)resid)[(size_t)grow * N + gcol + j];
                                if (RES == 2) v += b2f(((const unsigned short*)resid)[(size_t)grow * N + gcol + j]);
                                ps[j] = f2b(v);
                            }
                        }
                        *(uint4*)&co[(size_t)grow * N + gcol] = pk;
                    }
                }
        } else {
            // f32 out: 16 x 68 f32 slab; waves 0-6 in As[1], wave 7 in Bs[1]
            float* slabf = (w == 7) ? (float*)&Bs[1][0]
                                    : (float*)&As[1][0] + (size_t)w * 1088;
            float* co = (float*)Cout;
#pragma unroll
            for (int mh = 0; mh < 2; ++mh)
#pragma unroll
                for (int m = 0; m < 4; ++m) {
#pragma unroll
                    for (int nh = 0; nh < 2; ++nh)
#pragma unroll
                        for (int n = 0; n < 2; ++n)
#pragma unroll
                            for (int r2 = 0; r2 < 4; ++r2) {
                                float v = acc[mh * 4 + m][nh * 2 + n][r2];
                                if (BIAS) v += bshift[nh][n];
                                if (GELU) v = gelu_f(v);
                                slabf[(q * 4 + r2) * 68 + nh * 32 + n * 16 + l16] = v;
                            }
#pragma unroll
                    for (int i4 = 0; i4 < 4; ++i4) {
                        const int lr = i4 * 4 + (lane >> 4);
                        const int grow = tileM + wm + mh * 64 + m * 16 + lr;
                        const int gcol = tileN + wn + (lane & 15) * 4;
                        f32x4 vv = *(const f32x4*)&slabf[lr * 68 + (lane & 15) * 4];
                        if (RES == 1) {
                            const float4 r4 = *(const float4*)&((const float*)resid)[(size_t)grow * N + gcol];
                            vv[0] += r4.x; vv[1] += r4.y; vv[2] += r4.z; vv[3] += r4.w;
                        }
                        if (RES == 2) {
                            const ushort4 r4 = *(const ushort4*)&((const unsigned short*)resid)[(size_t)grow * N + gcol];
                            vv[0] += b2f(r4.x); vv[1] += b2f(r4.y); vv[2] += b2f(r4.z); vv[3] += b2f(r4.w);
                        }
                        *(f32x4*)&co[(size_t)grow * N + gcol] = vv;
                    }
                }
        }

        if (hasNext) {
            // drain epilogue stores/loads; keep the 4 staged loads (B_Q1,A_P1
            // of next k0) in flight -> K-loop vmcnt arithmetic stays exact.
            asm volatile("s_waitcnt vmcnt(4)" ::: "memory");
            __syncthreads();   // slab reads done before next ph0 DMA hits buf1
        }
    }
}

// ---------------- Attention: MFMA scores + in-register top-16 + softmax ----------------
__global__ __launch_bounds__(256) void attn_topk(const unsigned short* __restrict__ qk,
                                                 unsigned short* __restrict__ aout)
{
    const int bh = blockIdx.x;
    const int b = bh / NHEAD, h = bh % NHEAD;
    __shared__ __align__(16) unsigned short Qs[208 * 64];
    __shared__ __align__(16) unsigned short Ks[208 * 64];
    const int tid = threadIdx.x;

    for (int i = tid; i < 208 * 8; i += 256) {
        int row = i >> 3, c = i & 7;
        uint4 vq = make_uint4(0, 0, 0, 0), vk = vq;
        if (row < SEQ) {
            const uint4* gp = (const uint4*)(qk + ((size_t)(b * SEQ + row) * 1536 + h * 64));
            vq = gp[c];        // q half
            vk = gp[c + 96];   // k half: +768 shorts = +96 uint4
        }
        int slot = c ^ (row & 7);
        *(uint4*)&Qs[row * 64 + slot * 8] = vq;
        *(uint4*)&Ks[row * 64 + slot * 8] = vk;
    }
    __syncthreads();

    const int w = tid >> 6, lane = tid & 63;
    const int q = lane >> 4, l16 = lane & 15;

    for (int tn = w; tn < 13; tn += 4) {
        const int nrow = tn * 16 + l16;
        const int nsw = nrow & 7;
        bf16x8 bq0 = *(const bf16x8*)&Qs[nrow * 64 + ((0 * 4 + q) ^ nsw) * 8];
        bf16x8 bq1 = *(const bf16x8*)&Qs[nrow * 64 + ((1 * 4 + q) ^ nsw) * 8];

        float t[TOPK];
#pragma unroll
        for (int j = 0; j < TOPK; ++j) t[j] = NEGBIG;

        for (int tm = 0; tm < 12; ++tm) {
            const int mrow = tm * 16 + l16;
            const int msw = mrow & 7;
            bf16x8 ak0 = *(const bf16x8*)&Ks[mrow * 64 + ((0 * 4 + q) ^ msw) * 8];
            bf16x8 ak1 = *(const bf16x8*)&Ks[mrow * 64 + ((1 * 4 + q) ^ msw) * 8];
            f32x4 acc = (f32x4){0.f, 0.f, 0.f, 0.f};
            acc = __builtin_amdgcn_mfma_f32_16x16x32_bf16(ak0, bq0, acc, 0, 0, 0);
            acc = __builtin_amdgcn_mfma_f32_16x16x32_bf16(ak1, bq1, acc, 0, 0, 0);
#pragma unroll
            for (int r = 0; r < 4; ++r) {
                float v = acc[r];
#pragma unroll
                for (int j = 0; j < TOPK; ++j) {
                    float mx = fmaxf(t[j], v);
                    v = fminf(t[j], v);
                    t[j] = mx;
                }
            }
        }
        {   // m-tile 12: m = 192 + q*4 + r valid only for q==0
            const int mrow = 12 * 16 + l16;
            const int msw = mrow & 7;
            bf16x8 ak0 = *(const bf16x8*)&Ks[mrow * 64 + ((0 * 4 + q) ^ msw) * 8];
            bf16x8 ak1 = *(const bf16x8*)&Ks[mrow * 64 + ((1 * 4 + q) ^ msw) * 8];
            f32x4 acc = (f32x4){0.f, 0.f, 0.f, 0.f};
            acc = __builtin_amdgcn_mfma_f32_16x16x32_bf16(ak0, bq0, acc, 0, 0, 0);
            acc = __builtin_amdgcn_mfma_f32_16x16x32_bf16(ak1, bq1, acc, 0, 0, 0);
#pragma unroll
            for (int r = 0; r < 4; ++r) {
                float v = (q == 0) ? acc[r] : NEGBIG;
#pragma unroll
                for (int j = 0; j < TOPK; ++j) {
                    float mx = fmaxf(t[j], v);
                    v = fminf(t[j], v);
                    t[j] = mx;
                }
            }
        }

#pragma unroll
        for (int stage = 0; stage < 2; ++stage) {
            const int xm = 16 << stage;
            float bl[TOPK], c[TOPK];
#pragma unroll
            for (int j = 0; j < TOPK; ++j) bl[j] = __shfl_xor(t[j], xm, 64);
#pragma unroll
            for (int j = 0; j < TOPK; ++j) c[j] = fmaxf(t[j], bl[TOPK - 1 - j]);
#pragma unroll
            for (int s = 8; s >= 1; s >>= 1) {
#pragma unroll
                for (int i = 0; i < TOPK; ++i) {
                    if ((i & s) == 0) {
                        float mx = fmaxf(c[i], c[i + s]);
                        c[i + s] = fminf(c[i], c[i + s]);
                        c[i] = mx;
                    }
                }
            }
#pragma unroll
            for (int j = 0; j < TOPK; ++j) t[j] = c[j];
        }

        if (q == 0 && nrow < SEQ) {
            float e[TOPK], sum = 0.f;
#pragma unroll
            for (int j = 0; j < TOPK; ++j) { e[j] = __expf((t[j] - t[0]) * SCALE_F); sum += e[j]; }
            float inv = 1.0f / sum;
            unsigned int pk[8];
#pragma unroll
            for (int jj = 0; jj < 8; ++jj)
                pk[jj] = (unsigned int)f2b(e[2 * jj] * inv) |
                         ((unsigned int)f2b(e[2 * jj + 1] * inv) << 16);
            unsigned short* dst = aout + ((size_t)(b * SEQ + nrow)) * (NHEAD * TOPK) + h * TOPK;
            ((uint4*)dst)[0] = make_uint4(pk[0], pk[1], pk[2], pk[3]);
            ((uint4*)dst)[1] = make_uint4(pk[4], pk[5], pk[6], pk[7]);
        }
    }
}

// ---------------- Launch ----------------
extern "C" void kernel_launch(void* const* d_in, const int* in_sizes, int n_in,
                              void* d_out, int out_size, void* d_ws, size_t ws_size,
                              hipStream_t stream)
{
    const float* x    = (const float*)d_in[0];
    const float* g1   = (const float*)d_in[1];
    const float* bb1  = (const float*)d_in[2];
    const float* qkw  = (const float*)d_in[3];
    const float* pw   = (const float*)d_in[4];
    const float* pb   = (const float*)d_in[5];
    const float* g2   = (const float*)d_in[6];
    const float* bb2  = (const float*)d_in[7];
    const float* f1w  = (const float*)d_in[8];
    const float* f1b  = (const float*)d_in[9];
    const float* f2w  = (const float*)d_in[10];
    const float* f2bp = (const float*)d_in[11];
    float* out = (float*)d_out;

    // layout: hbuf | weights(wqk,wp,wf1,wf2) | av | qk/gg | x1b
    char* ws = (char*)d_ws;
    const size_t SZ_H   = (size_t)MROWS * CH * 2;              // 19,267,584
    const size_t N_WQK  = (size_t)2 * CH * CH;
    const size_t N_WP   = (size_t)CH * (NHEAD * TOPK);
    const size_t N_WF   = (size_t)HID * CH;
    const size_t SZ_W   = (N_WQK + N_WP + 2 * N_WF) * 2;       // 12,091,392
    const size_t SZ_A   = (size_t)MROWS * (NHEAD * TOPK) * 2;  //  4,816,896
    const size_t SZ_QK  = (size_t)MROWS * 2 * CH * 2;          // 38,535,168
    const size_t SZ_GGF = (size_t)MROWS * HID * 2;             // 77,070,336

    unsigned short* hbuf = (unsigned short*)(ws);
    unsigned short* wqk  = (unsigned short*)(ws + SZ_H);
    unsigned short* wp   = wqk + N_WQK;
    unsigned short* wf1  = wp  + N_WP;
    unsigned short* wf2  = wf1 + N_WF;
    unsigned short* av   = (unsigned short*)(ws + SZ_H + SZ_W);
    unsigned short* qk   = (unsigned short*)(ws + SZ_H + SZ_W + SZ_A);
    unsigned short* gg   = qk;   // overlays qk (dead by MLP time)

    const size_t base = SZ_H + SZ_W + SZ_A;
    const bool fullMLP = ws_size >= base + SZ_GGF + SZ_H;      // 132.5 MB: full-M + bf16 x1
    const bool bx1     = fullMLP || ws_size >= base + SZ_QK + SZ_H;  // 94 MB: halves + bf16 x1
    unsigned short* x1b = (unsigned short*)(ws + base + (fullMLP ? SZ_GGF : SZ_QK));
    float* x1 = out;   // f32 fallback residual lives in d_out

    // 0) all weights f32 -> bf16, one dispatch
    {
        int total4 = (int)((N_WQK + N_WP + 2 * N_WF) / 4);
        f2b4_k<<<(total4 + 255) / 256, 256, 0, stream>>>(
            qkw, wqk, (int)N_WQK, pw, wp, (int)N_WP,
            f1w, wf1, (int)N_WF, f2w, wf2, (int)N_WF);
    }

    // 1) LN1: x(f32) -> h (bf16)
    ln_k<true><<<MROWS, 256, 0, stream>>>(x, g1, bb1, hbuf);
    // 2) qk = h @ qk_w^T   [12544 x 1536], K=768   (persistent: 294 tiles on 256 blocks)
    gemm8p<CH, false, 0, false, false><<<256, 512, 0, stream>>>(
        hbuf, wqk, nullptr, nullptr, qk, MROWS, 2 * CH);
    // 3) attention -> top16 softmax weights [12544 x 192] bf16
    attn_topk<<<BATCH * NHEAD, 256, 0, stream>>>(qk, av);

    if (bx1) {
        // 4) x1b = bf16(x + a @ attn_proj_w^T + b)   (64x128: grid 6x196)
        gemm_bt<64, 128, true, 1, false, false><<<dim3(6, 196), 256, 0, stream>>>(
            av, wp, pb, x, x1b, MROWS, CH, NHEAD * TOPK);
        // 5) LN2: x1b (bf16) -> h2
        ln_k<false><<<MROWS, 256, 0, stream>>>(x1b, g2, bb2, hbuf);
        if (fullMLP) {
            // fc1: [12544 x 3072], K=768  (588 tiles on 256 blocks)
            gemm8p<CH, true, 0, true, false><<<256, 512, 0, stream>>>(
                hbuf, wf1, f1b, nullptr, gg, MROWS, HID);
            // fc2: [12544 x 768], K=3072 (147 tiles on 147 blocks)
            gemm8p<HID, true, 2, false, true><<<147, 512, 0, stream>>>(
                gg, wf2, f2bp, x1b, out, MROWS, CH);
        } else {
            for (int half = 0; half < 2; ++half) {
                const size_t ro = (size_t)half * MHALF;
                gemm_bt<128, 128, true, 0, true, false><<<dim3(24, 49), 256, 0, stream>>>(
                    hbuf + ro * CH, wf1, f1b, nullptr, gg, MHALF, HID, CH);
                gemm_bt<64, 256, true, 2, false, true><<<dim3(3, 98), 256, 0, stream>>>(
                    gg, wf2, f2bp, x1b + ro * CH, out + ro * CH, MHALF, CH, HID);
            }
        }
    } else {
        // conservative fallback: f32 x1 in d_out, halved MLP (74.7 MB ws)
        gemm_bt<64, 128, true, 1, false, true><<<dim3(6, 196), 256, 0, stream>>>(
            av, wp, pb, x, x1, MROWS, CH, NHEAD * TOPK);
        ln_k<true><<<MROWS, 256, 0, stream>>>(x1, g2, bb2, hbuf);
        for (int half = 0; half < 2; ++half) {
            const size_t ro = (size_t)half * MHALF;
            gemm_bt<128, 128, true, 0, true, false><<<dim3(24, 49), 256, 0, stream>>>(
                hbuf + ro * CH, wf1, f1b, nullptr, gg, MHALF, HID, CH);
            gemm_bt<64, 256, true, 1, false, true><<<dim3(3, 98), 256, 0, stream>>>(
                gg, wf2, f2bp, x1 + ro * CH, out + ro * CH, MHALF, CH, HID);
        }
    }
}

// Round 10
// 433.918 us; speedup vs baseline: 1.1274x; 1.1274x over previous
//
#include <hip/hip_runtime.h>

// Block_58394375356873: HomoAttention transformer block, MI355X gfx950.
// I/O dtype: float32 (per reference). Internal GEMM compute: bf16 MFMA;
// qk GEMM in fp8-e4m3 (R9). M = B*N = 64*196 = 12544.
//
// R9b: identical resubmission of R9 (prior bench was an infra failure —
// container never ran; no data). R9: revert gemm8p to R4-exact (swizzled
// staging — R8 proved removing the swizzle costs 26us of read conflicts and
// the DMA handles the XOR source fine). NEW: qk runs in fp8 e4m3 (gemm_f8) —
// same verified ring at HALF the staged bytes. Accuracy-safe: scores only
// feed top-16 + softmax. Subnormal dodge: weights x16, h x4 at conversion;
// softmax scale /4096 compensates.

#define BATCH 64
#define SEQ   196
#define CH    768
#define NHEAD 12
#define HDIM  64
#define TOPK  16
#define HID   3072
#define MROWS 12544
#define MHALF 6272
#define QK_SCALE (0.125f / 4096.0f)   // 0.125 / (16*4)^2 : fp8 pre-scaling folded in
#define NEGBIG -3e38f

typedef __bf16 bf16x8 __attribute__((ext_vector_type(8)));
typedef float  f32x4  __attribute__((ext_vector_type(4)));

__device__ __forceinline__ unsigned short f2b(float f) {
    union { float f; unsigned int i; } c; c.f = f;
    unsigned int u = c.i;
    return (unsigned short)((u + 0x7fffu + ((u >> 16) & 1u)) >> 16); // RNE
}
__device__ __forceinline__ float b2f(unsigned short u) {
    union { unsigned int i; float f; } c; c.i = ((unsigned int)u) << 16; return c.f;
}

// f32 -> fp8 e4m3 (OCP), RNE, saturating. Manual (no header dependency).
__device__ __forceinline__ unsigned char f2e4(float f) {
    union { float f; unsigned int u; } c; c.f = f;
    unsigned int s = (c.u >> 24) & 0x80u;
    float a = fabsf(f);
    if (!(a < 448.f)) return (unsigned char)(s | 0x7Eu);      // sat (NaN -> max)
    if (a < 0.015625f) {                                      // subnormal: step 2^-9
        int m = (int)rintf(a * 512.0f);                       // 0..8 (8 == 2^-6 normal)
        return (unsigned char)(s | (unsigned int)m);
    }
    unsigned int u = c.u & 0x7FFFFFFFu;
    u += 0x0FFFFFu + ((u >> 20) & 1u);                        // RNE into 3-bit mantissa
    int ee = (int)(u >> 23) - 127;
    if (ee > 8) return (unsigned char)(s | 0x7Eu);
    unsigned int mm = (u >> 20) & 7u;
    unsigned int enc = ((unsigned int)(ee + 7) << 3) | mm;
    if (enc > 0x7Eu) enc = 0x7Eu;                             // avoid NaN slot
    return (unsigned char)(s | enc);
}

// tanh-form GELU, |err vs exact erf-GELU| < 4e-4, ~10 VALU ops.
__device__ __forceinline__ float gelu_f(float v) {
    float u = v * (0.7978845608f + 0.0356774081f * v * v);
    float e = __expf(2.0f * u);
    float th = 1.0f - 2.0f / (e + 1.0f);
    return 0.5f * v * (1.0f + th);
}

// async global->LDS, 16B per lane. LDS base must be wave-uniform; HW adds lane*16.
__device__ __forceinline__ void async16(const unsigned short* g, unsigned short* l) {
    __builtin_amdgcn_global_load_lds(
        (const __attribute__((address_space(1))) unsigned int*)(g),
        (__attribute__((address_space(3))) unsigned int*)(l), 16, 0, 0);
}
__device__ __forceinline__ void async16b(const unsigned char* g, unsigned char* l) {
    __builtin_amdgcn_global_load_lds(
        (const __attribute__((address_space(1))) unsigned int*)(g),
        (__attribute__((address_space(3))) unsigned int*)(l), 16, 0, 0);
}

// ---------------- all-weights convert, one dispatch (seg0 -> fp8 x16, rest bf16) ----
__global__ __launch_bounds__(256) void f2b4_k(const float* __restrict__ s0, unsigned short* __restrict__ d0, int n0,
                                              const float* __restrict__ s1, unsigned short* __restrict__ d1, int n1,
                                              const float* __restrict__ s2, unsigned short* __restrict__ d2, int n2,
                                              const float* __restrict__ s3, unsigned short* __restrict__ d3, int n3)
{
    int idx = (blockIdx.x * 256 + threadIdx.x) * 4;
    const float* s; unsigned short* d; int n; int seg = 0;
    if (idx < n0) { s = s0; d = d0; n = n0; }
    else {
        idx -= n0; seg = 1;
        if (idx < n1) { s = s1; d = d1; n = n1; }
        else {
            idx -= n1; seg = 2;
            if (idx < n2) { s = s2; d = d2; n = n2; }
            else { idx -= n2; seg = 3; s = s3; d = d3; n = n3; }
        }
    }
    if (idx < n) {
        float4 v = *(const float4*)(s + idx);
        if (seg == 0) {   // qk weights -> fp8 e4m3, pre-scaled x16
            uchar4 o;
            o.x = f2e4(16.f * v.x); o.y = f2e4(16.f * v.y);
            o.z = f2e4(16.f * v.z); o.w = f2e4(16.f * v.w);
            *(uchar4*)((unsigned char*)d + idx) = o;
        } else {
            ushort4 o;
            o.x = f2b(v.x); o.y = f2b(v.y); o.z = f2b(v.z); o.w = f2b(v.w);
            *(ushort4*)(d + idx) = o;
        }
    }
}

// ---------------- LayerNorm: f32|bf16 in -> bf16|fp8 out, one block per row ------
// OUT8: fp8 e4m3 output, pre-scaled x4 (for the fp8 qk GEMM).
template<bool INF32, bool OUT8>
__global__ __launch_bounds__(256) void ln_k(const void* __restrict__ xin,
                                            const float* __restrict__ gw,
                                            const float* __restrict__ bw,
                                            void* __restrict__ out)
{
    const int row = blockIdx.x;
    const int tid = threadIdx.x;
    float v0, v1, v2;
    if constexpr (INF32) {
        const float* xr = (const float*)xin + (size_t)row * CH;
        v0 = xr[tid]; v1 = xr[tid + 256]; v2 = xr[tid + 512];
    } else {
        const unsigned short* xr = (const unsigned short*)xin + (size_t)row * CH;
        v0 = b2f(xr[tid]); v1 = b2f(xr[tid + 256]); v2 = b2f(xr[tid + 512]);
    }
    float s  = v0 + v1 + v2;
    float sq = v0*v0 + v1*v1 + v2*v2;
#pragma unroll
    for (int off = 32; off > 0; off >>= 1) {
        s  += __shfl_down(s, off, 64);
        sq += __shfl_down(sq, off, 64);
    }
    __shared__ __align__(16) float red[8];
    if ((tid & 63) == 0) { red[(tid >> 6) * 2] = s; red[(tid >> 6) * 2 + 1] = sq; }
    __syncthreads();
    s  = red[0] + red[2] + red[4] + red[6];
    sq = red[1] + red[3] + red[5] + red[7];
    float mu  = s * (1.0f / CH);
    float var = sq * (1.0f / CH) - mu * mu;
    float rs  = rsqrtf(var + 1e-5f);
    float y0 = (v0 - mu) * rs * gw[tid]       + bw[tid];
    float y1 = (v1 - mu) * rs * gw[tid + 256] + bw[tid + 256];
    float y2 = (v2 - mu) * rs * gw[tid + 512] + bw[tid + 512];
    if constexpr (OUT8) {
        unsigned char* orow = (unsigned char*)out + (size_t)row * CH;
        orow[tid]       = f2e4(4.f * y0);
        orow[tid + 256] = f2e4(4.f * y1);
        orow[tid + 512] = f2e4(4.f * y2);
    } else {
        unsigned short* orow = (unsigned short*)out + (size_t)row * CH;
        orow[tid]       = f2b(y0);
        orow[tid + 256] = f2b(y1);
        orow[tid + 512] = f2b(y2);
    }
}

// ---------------- NT GEMM (legacy 2-barrier): C = A @ W^T (+bias)(+gelu)(+resid) ----
// Kept for attn-proj (K=192) and halved fallback paths (M=6272 not /256).
template<int TM, int TN, bool BIAS, int RES, bool GELU, bool OUTF>
__global__ __launch_bounds__(256, 4)
void gemm_bt(const unsigned short* __restrict__ A,
             const unsigned short* __restrict__ Bw,
             const float* __restrict__ bias,
             const void* __restrict__ resid,
             void* __restrict__ Cout,
             int M, int N, int K)
{
    constexpr int WROWS = (TM == 128) ? 2 : 1;
    constexpr int WCOLS = 4 / WROWS;
    constexpr int JF = TN / (16 * WCOLS);
    __shared__ __align__(16) unsigned short As[2][TM * 32];
    __shared__ __align__(16) unsigned short Bs[2][TN * 32];
    const int tid  = threadIdx.x;
    const int w    = tid >> 6;
    const int lane = tid & 63;

    const int gridN = gridDim.x, gridM = gridDim.y;
    const int lid = blockIdx.y * gridN + blockIdx.x;
    const int SG = 8 * gridN;
    const int sg = lid / SG, r = lid % SG;
    const int remM = gridM - sg * 8;
    int mloc, nloc;
    if (remM >= 8) { mloc = sg * 8 + (r & 7); nloc = r >> 3; }
    else           { mloc = sg * 8 + r % remM; nloc = r / remM; }
    const int tileM = mloc * TM;
    const int tileN = nloc * TN;

    const int wm = (w / WCOLS) * 64;
    const int wn = (w % WCOLS) * (JF * 16);
    const int q   = lane >> 4;
    const int l16 = lane & 15;
    const int csw = (q ^ (l16 & 3)) * 8;

    f32x4 acc[4][JF];
#pragma unroll
    for (int i = 0; i < 4; ++i)
#pragma unroll
        for (int j = 0; j < JF; ++j) acc[i][j] = (f32x4){0.f, 0.f, 0.f, 0.f};

    const int r0 = tid >> 2;
    const int g0 = ((tid & 3) ^ (r0 & 3)) * 8;

    const unsigned short* pB[TN / 64];
    const unsigned short* pA[TM / 64];
#pragma unroll
    for (int c = 0; c < TN / 64; ++c) pB[c] = Bw + (size_t)(tileN + r0 + c * 64) * K + g0;
#pragma unroll
    for (int c = 0; c < TM / 64; ++c) pA[c] = A + (size_t)(tileM + r0 + c * 64) * K + g0;

    auto stage = [&](int buf) {
#pragma unroll
        for (int c = 0; c < TN / 64; ++c) {
            async16(pB[c], &Bs[buf][(size_t)(c * 256 + w * 64) * 8]);
            pB[c] += 32;
        }
#pragma unroll
        for (int c = 0; c < TM / 64; ++c) {
            async16(pA[c], &As[buf][(size_t)(c * 256 + w * 64) * 8]);
            pA[c] += 32;
        }
    };

    const int kIters = K >> 5;
    stage(0);
    int cur = 0;
    for (int kt = 0; kt < kIters; ++kt) {
        __syncthreads();
        if (kt + 1 < kIters) stage(cur ^ 1);
        bf16x8 af[4], bfr[JF];
#pragma unroll
        for (int i = 0; i < 4; ++i)
            af[i] = *(const bf16x8*)&As[cur][(wm + i * 16 + l16) * 32 + csw];
#pragma unroll
        for (int j = 0; j < JF; ++j)
            bfr[j] = *(const bf16x8*)&Bs[cur][(wn + j * 16 + l16) * 32 + csw];
#pragma unroll
        for (int i = 0; i < 4; ++i)
#pragma unroll
            for (int j = 0; j < JF; ++j)
                acc[i][j] = __builtin_amdgcn_mfma_f32_16x16x32_bf16(af[i], bfr[j], acc[i][j], 0, 0, 0);
        cur ^= 1;
    }

#pragma unroll
    for (int i = 0; i < 4; ++i) {
#pragma unroll
        for (int r2 = 0; r2 < 4; ++r2) {
            int row = tileM + wm + i * 16 + q * 4 + r2;
#pragma unroll
            for (int j = 0; j < JF; ++j) {
                int col = tileN + wn + j * 16 + l16;
                float v = acc[i][j][r2];
                if (BIAS) v += bias[col];
                if (GELU) v = gelu_f(v);
                if (RES == 1) v += ((const float*)resid)[(size_t)row * N + col];
                if (RES == 2) v += b2f(((const unsigned short*)resid)[(size_t)row * N + col]);
                if (OUTF) ((float*)Cout)[(size_t)row * N + col] = v;
                else      ((unsigned short*)Cout)[(size_t)row * N + col] = f2b(v);
            }
        }
    }
}

// ---------------- Persistent 4-phase 256x256 NT GEMM (R4-exact, bf16) ----------------
template<int KC, bool BIAS, int RES, bool GELU, bool OUTF>
__global__ __launch_bounds__(512, 2)
void gemm8p(const unsigned short* __restrict__ A,
            const unsigned short* __restrict__ Bw,
            const float* __restrict__ bias,
            const void* __restrict__ resid,
            void* __restrict__ Cout,
            int M, int N)
{
    constexpr int T = KC / 64;
    static_assert((T & 1) == 0, "T must be even for persistent parity");
    __shared__ __align__(16) unsigned short As[2][256 * 64];
    __shared__ __align__(16) unsigned short Bs[2][256 * 64];
    const int tid  = threadIdx.x;
    const int w    = tid >> 6;
    const int lane = tid & 63;
    const int q    = lane >> 4;
    const int l16  = lane & 15;

    const int gridN = N >> 8, gridM = M >> 8;
    const int nt = gridN * gridM;
    const int P = gridDim.x;

    auto tileOf = [&](int lid2, int& tm, int& tn) {
        const int SG = 8 * gridN;
        const int sg = lid2 / SG, rr2 = lid2 % SG;
        const int remM = gridM - sg * 8;
        int mloc, nloc;
        if (remM >= 8) { mloc = sg * 8 + (rr2 & 7); nloc = rr2 >> 3; }
        else           { mloc = sg * 8 + rr2 % remM; nloc = rr2 / remM; }
        tm = mloc * 256; tn = nloc * 256;
    };

    const int wm = (w >> 2) * 128;
    const int wn = (w & 3) * 64;

    const int r0 = tid >> 3;
    const int g0 = (tid & 7) ^ (r0 & 7);
    const int rB = r0 + (r0 & 32);

    const int arow = wm + l16;
    const int brow = wn + l16;
    const int xsw  = l16 & 7;

    for (int t = (int)blockIdx.x; t < nt; t += P) {
        int tileM, tileN;
        tileOf(t, tileM, tileN);
        const bool hasNext = (t + P) < nt;
        int tileM2 = tileM, tileN2 = tileN;
        if (hasNext) tileOf(t + P, tileM2, tileN2);

        const unsigned short* pA0  = A  + (size_t)(tileM  + r0) * KC + g0 * 8;
        const unsigned short* pB0  = Bw + (size_t)(tileN  + rB) * KC + g0 * 8;
        const unsigned short* pA0n = A  + (size_t)(tileM2 + r0) * KC + g0 * 8;
        const unsigned short* pB0n = Bw + (size_t)(tileN2 + rB) * KC + g0 * 8;

        auto stageA = [&](int v, int j) {
            const unsigned short* base = (v == T) ? pA0n : pA0;
            const int vv = (v == T) ? 0 : v;
            const unsigned short* s = base + (size_t)(j * 64) * KC + vv * 64;
            unsigned short* d = As[vv & 1] + j * 4096 + w * 512;
            async16(s, d);
            async16(s + (size_t)128 * KC, d + 8192);
        };
        auto stageB = [&](int v, int j) {
            const unsigned short* base = (v == T) ? pB0n : pB0;
            const int vv = (v == T) ? 0 : v;
            const unsigned short* s = base + (size_t)(j * 32) * KC + vv * 64;
            unsigned short* d = Bs[vv & 1] + j * 2048 + (w * 8 + ((w & 4) << 3)) * 64;
            async16(s, d);
            async16(s + (size_t)128 * KC, d + 8192);
        };

        f32x4 acc[8][4];
#pragma unroll
        for (int i = 0; i < 8; ++i)
#pragma unroll
            for (int jn = 0; jn < 4; ++jn) acc[i][jn] = (f32x4){0.f, 0.f, 0.f, 0.f};

        if (t == (int)blockIdx.x) {
            stageA(0, 0); stageB(0, 0); stageB(0, 1); stageA(0, 1);
            asm volatile("s_waitcnt vmcnt(4)" ::: "memory");
            __builtin_amdgcn_s_barrier();
            asm volatile("" ::: "memory");
        }

#pragma unroll 2
        for (int u = 0; u < T; ++u) {
            const unsigned short* Ab = As[u & 1];
            const unsigned short* Bb = Bs[u & 1];
            const bool more = (u + 1 < T) || hasNext;
            bf16x8 af[4][2], b0[2][2], b1[2][2];

            // ---------- ph0 ----------
#pragma unroll
            for (int m = 0; m < 4; ++m)
#pragma unroll
                for (int kk = 0; kk < 2; ++kk)
                    af[m][kk] = *(const bf16x8*)&Ab[(arow + m * 16) * 64 + ((((kk << 2) | q) ^ xsw) << 3)];
#pragma unroll
            for (int n = 0; n < 2; ++n)
#pragma unroll
                for (int kk = 0; kk < 2; ++kk)
                    b0[n][kk] = *(const bf16x8*)&Bb[(brow + n * 16) * 64 + ((((kk << 2) | q) ^ xsw) << 3)];
            if (more) stageA(u + 1, 0);
            __builtin_amdgcn_s_setprio(1);
#pragma unroll
            for (int kk = 0; kk < 2; ++kk)
#pragma unroll
                for (int m = 0; m < 4; ++m)
#pragma unroll
                    for (int n = 0; n < 2; ++n)
                        acc[m][n] = __builtin_amdgcn_mfma_f32_16x16x32_bf16(af[m][kk], b0[n][kk], acc[m][n], 0, 0, 0);
            __builtin_amdgcn_s_setprio(0);

            // ---------- ph1 ----------
            if (more) asm volatile("s_waitcnt vmcnt(4)" ::: "memory");
            else      asm volatile("s_waitcnt vmcnt(2)" ::: "memory");
            __builtin_amdgcn_s_barrier();
            asm volatile("" ::: "memory");
#pragma unroll
            for (int n = 0; n < 2; ++n)
#pragma unroll
                for (int kk = 0; kk < 2; ++kk)
                    b1[n][kk] = *(const bf16x8*)&Bb[(brow + 32 + n * 16) * 64 + ((((kk << 2) | q) ^ xsw) << 3)];
            if (more) stageB(u + 1, 0);
            __builtin_amdgcn_s_setprio(1);
#pragma unroll
            for (int kk = 0; kk < 2; ++kk)
#pragma unroll
                for (int m = 0; m < 4; ++m)
#pragma unroll
                    for (int n = 0; n < 2; ++n)
                        acc[m][2 + n] = __builtin_amdgcn_mfma_f32_16x16x32_bf16(af[m][kk], b1[n][kk], acc[m][2 + n], 0, 0, 0);
            __builtin_amdgcn_s_setprio(0);

            // ---------- ph2 ----------
            if (more) asm volatile("s_waitcnt vmcnt(4)" ::: "memory");
            else      asm volatile("s_waitcnt vmcnt(0)" ::: "memory");
            __builtin_amdgcn_s_barrier();
            asm volatile("" ::: "memory");
#pragma unroll
            for (int m = 0; m < 4; ++m)
#pragma unroll
                for (int kk = 0; kk < 2; ++kk)
                    af[m][kk] = *(const bf16x8*)&Ab[(arow + 64 + m * 16) * 64 + ((((kk << 2) | q) ^ xsw) << 3)];
            if (more) stageB(u + 1, 1);
            __builtin_amdgcn_s_setprio(1);
#pragma unroll
            for (int kk = 0; kk < 2; ++kk)
#pragma unroll
                for (int m = 0; m < 4; ++m)
#pragma unroll
                    for (int n = 0; n < 2; ++n)
                        acc[4 + m][2 + n] = __builtin_amdgcn_mfma_f32_16x16x32_bf16(af[m][kk], b1[n][kk], acc[4 + m][2 + n], 0, 0, 0);
            __builtin_amdgcn_s_setprio(0);

            // ---------- ph3 ----------
            if (more) {
                stageA(u + 1, 1);
                asm volatile("s_waitcnt vmcnt(4)" ::: "memory");
                __builtin_amdgcn_s_barrier();
                asm volatile("" ::: "memory");
            }
            __builtin_amdgcn_s_setprio(1);
#pragma unroll
            for (int kk = 0; kk < 2; ++kk)
#pragma unroll
                for (int m = 0; m < 4; ++m)
#pragma unroll
                    for (int n = 0; n < 2; ++n)
                        acc[4 + m][n] = __builtin_amdgcn_mfma_f32_16x16x32_bf16(af[m][kk], b0[n][kk], acc[4 + m][n], 0, 0, 0);
            __builtin_amdgcn_s_setprio(0);
        }

        // ---------------- coalesced epilogue ----------------
        __syncthreads();

        float bshift[2][2];
        if (BIAS) {
#pragma unroll
            for (int nh = 0; nh < 2; ++nh)
#pragma unroll
                for (int n = 0; n < 2; ++n)
                    bshift[nh][n] = bias[tileN + wn + nh * 32 + n * 16 + l16];
        }

        if constexpr (!OUTF) {
            unsigned short* slab = &As[1][0] + (size_t)w * 1152;
            unsigned short* co = (unsigned short*)Cout;
#pragma unroll
            for (int mh = 0; mh < 2; ++mh)
#pragma unroll
                for (int m = 0; m < 4; ++m) {
#pragma unroll
                    for (int nh = 0; nh < 2; ++nh)
#pragma unroll
                        for (int n = 0; n < 2; ++n)
#pragma unroll
                            for (int r2 = 0; r2 < 4; ++r2) {
                                float v = acc[mh * 4 + m][nh * 2 + n][r2];
                                if (BIAS) v += bshift[nh][n];
                                if (GELU) v = gelu_f(v);
                                slab[(q * 4 + r2) * 72 + nh * 32 + n * 16 + l16] = f2b(v);
                            }
#pragma unroll
                    for (int h = 0; h < 2; ++h) {
                        const int lr = h * 8 + (lane >> 3);
                        const int grow = tileM + wm + mh * 64 + m * 16 + lr;
                        const int gcol = tileN + wn + (lane & 7) * 8;
                        uint4 pk = *(const uint4*)&slab[lr * 72 + (lane & 7) * 8];
                        if (RES != 0) {
                            unsigned short* ps = (unsigned short*)&pk;
#pragma unroll
                            for (int j = 0; j < 8; ++j) {
                                float v = b2f(ps[j]);
                                if (RES == 1) v += ((const float*)resid)[(size_t)grow * N + gcol + j];
                                if (RES == 2) v += b2f(((const unsigned short*)resid)[(size_t)grow * N + gcol + j]);
                                ps[j] = f2b(v);
                            }
                        }
                        *(uint4*)&co[(size_t)grow * N + gcol] = pk;
                    }
                }
        } else {
            float* slabf = (w == 7) ? (float*)&Bs[1][0]
                                    : (float*)&As[1][0] + (size_t)w * 1088;
            float* co = (float*)Cout;
#pragma unroll
            for (int mh = 0; mh < 2; ++mh)
#pragma unroll
                for (int m = 0; m < 4; ++m) {
#pragma unroll
                    for (int nh = 0; nh < 2; ++nh)
#pragma unroll
                        for (int n = 0; n < 2; ++n)
#pragma unroll
                            for (int r2 = 0; r2 < 4; ++r2) {
                                float v = acc[mh * 4 + m][nh * 2 + n][r2];
                                if (BIAS) v += bshift[nh][n];
                                if (GELU) v = gelu_f(v);
                                slabf[(q * 4 + r2) * 68 + nh * 32 + n * 16 + l16] = v;
                            }
#pragma unroll
                    for (int i4 = 0; i4 < 4; ++i4) {
                        const int lr = i4 * 4 + (lane >> 4);
                        const int grow = tileM + wm + mh * 64 + m * 16 + lr;
                        const int gcol = tileN + wn + (lane & 15) * 4;
                        f32x4 vv = *(const f32x4*)&slabf[lr * 68 + (lane & 15) * 4];
                        if (RES == 1) {
                            const float4 r4 = *(const float4*)&((const float*)resid)[(size_t)grow * N + gcol];
                            vv[0] += r4.x; vv[1] += r4.y; vv[2] += r4.z; vv[3] += r4.w;
                        }
                        if (RES == 2) {
                            const ushort4 r4 = *(const ushort4*)&((const unsigned short*)resid)[(size_t)grow * N + gcol];
                            vv[0] += b2f(r4.x); vv[1] += b2f(r4.y); vv[2] += b2f(r4.z); vv[3] += b2f(r4.w);
                        }
                        *(f32x4*)&co[(size_t)grow * N + gcol] = vv;
                    }
                }
        }

        if (hasNext) {
            asm volatile("s_waitcnt vmcnt(4)" ::: "memory");
            __syncthreads();
        }
    }
}

// ---------------- Persistent 4-phase 256x256 NT GEMM, fp8 e4m3 (qk only) -------------
// Same ring/waits as gemm8p at half the bytes. KC=768 (T=12). LDS 64KB.
// Staging: one async16 per quarter (512 thr x 16B = 8KB); 16B-chunk XOR swizzle
// (4 chunks/row): slot = chunk ^ (row&3), applied via pre-swizzled source.
// Frags: 8 fp8 per lane (ds_read b64) at k-offset q*8 in each 32-K window.
__global__ __launch_bounds__(512, 2)
void gemm_f8(const unsigned char* __restrict__ A,
             const unsigned char* __restrict__ Bw,
             unsigned short* __restrict__ Cout,
             int M, int N)
{
    constexpr int KC = 768;
    constexpr int T = 12;
    __shared__ __align__(16) unsigned char As[2][256 * 64];
    __shared__ __align__(16) unsigned char Bs[2][256 * 64];
    const int tid  = threadIdx.x;
    const int w    = tid >> 6;
    const int lane = tid & 63;
    const int q    = lane >> 4;
    const int l16  = lane & 15;

    const int gridN = N >> 8, gridM = M >> 8;
    const int nt = gridN * gridM;
    const int P = gridDim.x;

    auto tileOf = [&](int lid2, int& tm, int& tn) {
        const int SG = 8 * gridN;
        const int sg = lid2 / SG, rr2 = lid2 % SG;
        const int remM = gridM - sg * 8;
        int mloc, nloc;
        if (remM >= 8) { mloc = sg * 8 + (rr2 & 7); nloc = rr2 >> 3; }
        else           { mloc = sg * 8 + rr2 % remM; nloc = rr2 / remM; }
        tm = mloc * 256; tn = nloc * 256;
    };

    const int wm = (w >> 2) * 128;
    const int wn = (w & 3) * 64;

    // staging lane geometry: lr = lane>>2 (row in 16-row wave span), sc = lane&3 (slot)
    const int lr  = lane >> 2;
    const int ssw = ((lane & 3) ^ (lr & 3)) << 4;      // pre-swizzled src chunk offset
    // wave row bases
    const int rbA = (w & 3) * 16 + ((w >> 2) << 7);    // + j*64 per call
    const int rbB = ((w >> 1) << 6) + ((w & 1) << 4);  // + j*32 per call

    const int arow = wm + l16;
    const int brow = wn + l16;
    const int xsw3 = l16 & 3;

    for (int t = (int)blockIdx.x; t < nt; t += P) {
        int tileM, tileN;
        tileOf(t, tileM, tileN);
        const bool hasNext = (t + P) < nt;
        int tileM2 = tileM, tileN2 = tileN;
        if (hasNext) tileOf(t + P, tileM2, tileN2);

        const unsigned char* pA0  = A  + (size_t)(tileM  + lr) * KC + ssw;
        const unsigned char* pB0  = Bw + (size_t)(tileN  + lr) * KC + ssw;
        const unsigned char* pA0n = A  + (size_t)(tileM2 + lr) * KC + ssw;
        const unsigned char* pB0n = Bw + (size_t)(tileN2 + lr) * KC + ssw;

        // A quarter j: LDS rows {j*64..+63} u {128+j*64..+63}; one 8KB DMA call.
        auto stageA = [&](int v, int j) {
            const unsigned char* base = (v == T) ? pA0n : pA0;
            const int vv = (v == T) ? 0 : v;
            const int rb = rbA + j * 64;               // this wave's 16-row base
            async16b(base + (size_t)rb * KC + vv * 64, As[vv & 1] + rb * 64);
        };
        // B quarter j: LDS rows (bit5==j); one 8KB DMA call.
        auto stageB = [&](int v, int j) {
            const unsigned char* base = (v == T) ? pB0n : pB0;
            const int vv = (v == T) ? 0 : v;
            const int rb = rbB + j * 32;
            async16b(base + (size_t)rb * KC + vv * 64, Bs[vv & 1] + rb * 64);
        };

        f32x4 acc[8][4];
#pragma unroll
        for (int i = 0; i < 8; ++i)
#pragma unroll
            for (int jn = 0; jn < 4; ++jn) acc[i][jn] = (f32x4){0.f, 0.f, 0.f, 0.f};

        if (t == (int)blockIdx.x) {
            stageA(0, 0); stageB(0, 0); stageB(0, 1); stageA(0, 1);
            asm volatile("s_waitcnt vmcnt(2)" ::: "memory");
            __builtin_amdgcn_s_barrier();
            asm volatile("" ::: "memory");
        }

        // frag byte offset within a row: chunk (kk*2 + q>>1) XOR row&3, + (q&1)*8
        auto foff = [&](int kk) {
            return ((((kk << 1) | (q >> 1)) ^ xsw3) << 4) + ((q & 1) << 3);
        };

#pragma unroll 2
        for (int u = 0; u < T; ++u) {
            const unsigned char* Ab = As[u & 1];
            const unsigned char* Bb = Bs[u & 1];
            const bool more = (u + 1 < T) || hasNext;
            long af[4][2], b0[2][2], b1[2][2];

            // ---------- ph0 ----------
#pragma unroll
            for (int m = 0; m < 4; ++m)
#pragma unroll
                for (int kk = 0; kk < 2; ++kk)
                    af[m][kk] = *(const long*)&Ab[(arow + m * 16) * 64 + foff(kk)];
#pragma unroll
            for (int n = 0; n < 2; ++n)
#pragma unroll
                for (int kk = 0; kk < 2; ++kk)
                    b0[n][kk] = *(const long*)&Bb[(brow + n * 16) * 64 + foff(kk)];
            if (more) stageA(u + 1, 0);
            __builtin_amdgcn_s_setprio(1);
#pragma unroll
            for (int kk = 0; kk < 2; ++kk)
#pragma unroll
                for (int m = 0; m < 4; ++m)
#pragma unroll
                    for (int n = 0; n < 2; ++n)
                        acc[m][n] = __builtin_amdgcn_mfma_f32_16x16x32_fp8_fp8(af[m][kk], b0[n][kk], acc[m][n], 0, 0, 0);
            __builtin_amdgcn_s_setprio(0);

            // ---------- ph1 ----------
            if (more) asm volatile("s_waitcnt vmcnt(2)" ::: "memory");
            else      asm volatile("s_waitcnt vmcnt(1)" ::: "memory");
            __builtin_amdgcn_s_barrier();
            asm volatile("" ::: "memory");
#pragma unroll
            for (int n = 0; n < 2; ++n)
#pragma unroll
                for (int kk = 0; kk < 2; ++kk)
                    b1[n][kk] = *(const long*)&Bb[(brow + 32 + n * 16) * 64 + foff(kk)];
            if (more) stageB(u + 1, 0);
            __builtin_amdgcn_s_setprio(1);
#pragma unroll
            for (int kk = 0; kk < 2; ++kk)
#pragma unroll
                for (int m = 0; m < 4; ++m)
#pragma unroll
                    for (int n = 0; n < 2; ++n)
                        acc[m][2 + n] = __builtin_amdgcn_mfma_f32_16x16x32_fp8_fp8(af[m][kk], b1[n][kk], acc[m][2 + n], 0, 0, 0);
            __builtin_amdgcn_s_setprio(0);

            // ---------- ph2 ----------
            if (more) asm volatile("s_waitcnt vmcnt(2)" ::: "memory");
            else      asm volatile("s_waitcnt vmcnt(0)" ::: "memory");
            __builtin_amdgcn_s_barrier();
            asm volatile("" ::: "memory");
#pragma unroll
            for (int m = 0; m < 4; ++m)
#pragma unroll
                for (int kk = 0; kk < 2; ++kk)
                    af[m][kk] = *(const long*)&Ab[(arow + 64 + m * 16) * 64 + foff(kk)];
            if (more) stageB(u + 1, 1);
            __builtin_amdgcn_s_setprio(1);
#pragma unroll
            for (int kk = 0; kk < 2; ++kk)
#pragma unroll
                for (int m = 0; m < 4; ++m)
#pragma unroll
                    for (int n = 0; n < 2; ++n)
                        acc[4 + m][2 + n] = __builtin_amdgcn_mfma_f32_16x16x32_fp8_fp8(af[m][kk], b1[n][kk], acc[4 + m][2 + n], 0, 0, 0);
            __builtin_amdgcn_s_setprio(0);

            // ---------- ph3 ----------
            if (more) {
                stageA(u + 1, 1);
                asm volatile("s_waitcnt vmcnt(2)" ::: "memory");
                __builtin_amdgcn_s_barrier();
                asm volatile("" ::: "memory");
            }
            __builtin_amdgcn_s_setprio(1);
#pragma unroll
            for (int kk = 0; kk < 2; ++kk)
#pragma unroll
                for (int m = 0; m < 4; ++m)
#pragma unroll
                    for (int n = 0; n < 2; ++n)
                        acc[4 + m][n] = __builtin_amdgcn_mfma_f32_16x16x32_fp8_fp8(af[m][kk], b0[n][kk], acc[4 + m][n], 0, 0, 0);
            __builtin_amdgcn_s_setprio(0);
        }

        // ---------------- coalesced epilogue (bf16 out; slab in buf1) ----------------
        __syncthreads();

        unsigned short* slab = (w == 7) ? (unsigned short*)&Bs[1][0]
                                        : (unsigned short*)&As[1][0] + (size_t)w * 1152;
#pragma unroll
        for (int mh = 0; mh < 2; ++mh)
#pragma unroll
            for (int m = 0; m < 4; ++m) {
#pragma unroll
                for (int nh = 0; nh < 2; ++nh)
#pragma unroll
                    for (int n = 0; n < 2; ++n)
#pragma unroll
                        for (int r2 = 0; r2 < 4; ++r2)
                            slab[(q * 4 + r2) * 72 + nh * 32 + n * 16 + l16] =
                                f2b(acc[mh * 4 + m][nh * 2 + n][r2]);
#pragma unroll
                for (int h = 0; h < 2; ++h) {
                    const int lrr = h * 8 + (lane >> 3);
                    const int grow = tileM + wm + mh * 64 + m * 16 + lrr;
                    const int gcol = tileN + wn + (lane & 7) * 8;
                    uint4 pk = *(const uint4*)&slab[lrr * 72 + (lane & 7) * 8];
                    *(uint4*)&Cout[(size_t)grow * N + gcol] = pk;
                }
            }

        if (hasNext) {
            asm volatile("s_waitcnt vmcnt(2)" ::: "memory");
            __syncthreads();
        }
    }
}

// ---------------- Attention: MFMA scores + in-register top-16 + softmax ----------------
__global__ __launch_bounds__(256) void attn_topk(const unsigned short* __restrict__ qk,
                                                 unsigned short* __restrict__ aout)
{
    const int bh = blockIdx.x;
    const int b = bh / NHEAD, h = bh % NHEAD;
    __shared__ __align__(16) unsigned short Qs[208 * 64];
    __shared__ __align__(16) unsigned short Ks[208 * 64];
    const int tid = threadIdx.x;

    for (int i = tid; i < 208 * 8; i += 256) {
        int row = i >> 3, c = i & 7;
        uint4 vq = make_uint4(0, 0, 0, 0), vk = vq;
        if (row < SEQ) {
            const uint4* gp = (const uint4*)(qk + ((size_t)(b * SEQ + row) * 1536 + h * 64));
            vq = gp[c];
            vk = gp[c + 96];
        }
        int slot = c ^ (row & 7);
        *(uint4*)&Qs[row * 64 + slot * 8] = vq;
        *(uint4*)&Ks[row * 64 + slot * 8] = vk;
    }
    __syncthreads();

    const int w = tid >> 6, lane = tid & 63;
    const int q = lane >> 4, l16 = lane & 15;

    for (int tn = w; tn < 13; tn += 4) {
        const int nrow = tn * 16 + l16;
        const int nsw = nrow & 7;
        bf16x8 bq0 = *(const bf16x8*)&Qs[nrow * 64 + ((0 * 4 + q) ^ nsw) * 8];
        bf16x8 bq1 = *(const bf16x8*)&Qs[nrow * 64 + ((1 * 4 + q) ^ nsw) * 8];

        float t[TOPK];
#pragma unroll
        for (int j = 0; j < TOPK; ++j) t[j] = NEGBIG;

        for (int tm = 0; tm < 12; ++tm) {
            const int mrow = tm * 16 + l16;
            const int msw = mrow & 7;
            bf16x8 ak0 = *(const bf16x8*)&Ks[mrow * 64 + ((0 * 4 + q) ^ msw) * 8];
            bf16x8 ak1 = *(const bf16x8*)&Ks[mrow * 64 + ((1 * 4 + q) ^ msw) * 8];
            f32x4 acc = (f32x4){0.f, 0.f, 0.f, 0.f};
            acc = __builtin_amdgcn_mfma_f32_16x16x32_bf16(ak0, bq0, acc, 0, 0, 0);
            acc = __builtin_amdgcn_mfma_f32_16x16x32_bf16(ak1, bq1, acc, 0, 0, 0);
#pragma unroll
            for (int r = 0; r < 4; ++r) {
                float v = acc[r];
#pragma unroll
                for (int j = 0; j < TOPK; ++j) {
                    float mx = fmaxf(t[j], v);
                    v = fminf(t[j], v);
                    t[j] = mx;
                }
            }
        }
        {   // m-tile 12: m = 192 + q*4 + r valid only for q==0
            const int mrow = 12 * 16 + l16;
            const int msw = mrow & 7;
            bf16x8 ak0 = *(const bf16x8*)&Ks[mrow * 64 + ((0 * 4 + q) ^ msw) * 8];
            bf16x8 ak1 = *(const bf16x8*)&Ks[mrow * 64 + ((1 * 4 + q) ^ msw) * 8];
            f32x4 acc = (f32x4){0.f, 0.f, 0.f, 0.f};
            acc = __builtin_amdgcn_mfma_f32_16x16x32_bf16(ak0, bq0, acc, 0, 0, 0);
            acc = __builtin_amdgcn_mfma_f32_16x16x32_bf16(ak1, bq1, acc, 0, 0, 0);
#pragma unroll
            for (int r = 0; r < 4; ++r) {
                float v = (q == 0) ? acc[r] : NEGBIG;
#pragma unroll
                for (int j = 0; j < TOPK; ++j) {
                    float mx = fmaxf(t[j], v);
                    v = fminf(t[j], v);
                    t[j] = mx;
                }
            }
        }

#pragma unroll
        for (int stage = 0; stage < 2; ++stage) {
            const int xm = 16 << stage;
            float bl[TOPK], c[TOPK];
#pragma unroll
            for (int j = 0; j < TOPK; ++j) bl[j] = __shfl_xor(t[j], xm, 64);
#pragma unroll
            for (int j = 0; j < TOPK; ++j) c[j] = fmaxf(t[j], bl[TOPK - 1 - j]);
#pragma unroll
            for (int s = 8; s >= 1; s >>= 1) {
#pragma unroll
                for (int i = 0; i < TOPK; ++i) {
                    if ((i & s) == 0) {
                        float mx = fmaxf(c[i], c[i + s]);
                        c[i + s] = fminf(c[i], c[i + s]);
                        c[i] = mx;
                    }
                }
            }
#pragma unroll
            for (int j = 0; j < TOPK; ++j) t[j] = c[j];
        }

        if (q == 0 && nrow < SEQ) {
            float e[TOPK], sum = 0.f;
#pragma unroll
            for (int j = 0; j < TOPK; ++j) { e[j] = __expf((t[j] - t[0]) * QK_SCALE); sum += e[j]; }
            float inv = 1.0f / sum;
            unsigned int pk[8];
#pragma unroll
            for (int jj = 0; jj < 8; ++jj)
                pk[jj] = (unsigned int)f2b(e[2 * jj] * inv) |
                         ((unsigned int)f2b(e[2 * jj + 1] * inv) << 16);
            unsigned short* dst = aout + ((size_t)(b * SEQ + nrow)) * (NHEAD * TOPK) + h * TOPK;
            ((uint4*)dst)[0] = make_uint4(pk[0], pk[1], pk[2], pk[3]);
            ((uint4*)dst)[1] = make_uint4(pk[4], pk[5], pk[6], pk[7]);
        }
    }
}

// ---------------- Launch ----------------
extern "C" void kernel_launch(void* const* d_in, const int* in_sizes, int n_in,
                              void* d_out, int out_size, void* d_ws, size_t ws_size,
                              hipStream_t stream)
{
    const float* x    = (const float*)d_in[0];
    const float* g1   = (const float*)d_in[1];
    const float* bb1  = (const float*)d_in[2];
    const float* qkw  = (const float*)d_in[3];
    const float* pw   = (const float*)d_in[4];
    const float* pb   = (const float*)d_in[5];
    const float* g2   = (const float*)d_in[6];
    const float* bb2  = (const float*)d_in[7];
    const float* f1w  = (const float*)d_in[8];
    const float* f1b  = (const float*)d_in[9];
    const float* f2w  = (const float*)d_in[10];
    const float* f2bp = (const float*)d_in[11];
    float* out = (float*)d_out;

    // layout: hbuf | weights(wqk,wp,wf1,wf2) | av | qk/gg | x1b
    char* ws = (char*)d_ws;
    const size_t SZ_H   = (size_t)MROWS * CH * 2;              // 19,267,584
    const size_t N_WQK  = (size_t)2 * CH * CH;
    const size_t N_WP   = (size_t)CH * (NHEAD * TOPK);
    const size_t N_WF   = (size_t)HID * CH;
    const size_t SZ_W   = (N_WQK + N_WP + 2 * N_WF) * 2;       // 12,091,392
    const size_t SZ_A   = (size_t)MROWS * (NHEAD * TOPK) * 2;  //  4,816,896
    const size_t SZ_QK  = (size_t)MROWS * 2 * CH * 2;          // 38,535,168
    const size_t SZ_GGF = (size_t)MROWS * HID * 2;             // 77,070,336

    unsigned short* hbuf = (unsigned short*)(ws);              // LN2 bf16 / LN1 fp8
    unsigned char*  hbuf8 = (unsigned char*)(ws);
    unsigned short* wqk  = (unsigned short*)(ws + SZ_H);       // region holds fp8 now
    unsigned char*  wqk8 = (unsigned char*)(ws + SZ_H);
    unsigned short* wp   = wqk + N_WQK;
    unsigned short* wf1  = wp  + N_WP;
    unsigned short* wf2  = wf1 + N_WF;
    unsigned short* av   = (unsigned short*)(ws + SZ_H + SZ_W);
    unsigned short* qk   = (unsigned short*)(ws + SZ_H + SZ_W + SZ_A);
    unsigned short* gg   = qk;   // overlays qk (dead by MLP time)

    const size_t base = SZ_H + SZ_W + SZ_A;
    const bool fullMLP = ws_size >= base + SZ_GGF + SZ_H;
    const bool bx1     = fullMLP || ws_size >= base + SZ_QK + SZ_H;
    unsigned short* x1b = (unsigned short*)(ws + base + (fullMLP ? SZ_GGF : SZ_QK));
    float* x1 = out;

    // 0) all weights convert: wqk -> fp8(x16), others bf16
    {
        int total4 = (int)((N_WQK + N_WP + 2 * N_WF) / 4);
        f2b4_k<<<(total4 + 255) / 256, 256, 0, stream>>>(
            qkw, wqk, (int)N_WQK, pw, wp, (int)N_WP,
            f1w, wf1, (int)N_WF, f2w, wf2, (int)N_WF);
    }

    // 1) LN1: x(f32) -> h (fp8 e4m3, x4)
    ln_k<true, true><<<MROWS, 256, 0, stream>>>(x, g1, bb1, hbuf8);
    // 2) qk = h @ qk_w^T  [12544 x 1536], K=768, fp8 (294 tiles on 256 blocks)
    gemm_f8<<<256, 512, 0, stream>>>(hbuf8, wqk8, qk, MROWS, 2 * CH);
    // 3) attention -> top16 softmax weights [12544 x 192] bf16 (QK_SCALE folds fp8 pre-scale)
    attn_topk<<<BATCH * NHEAD, 256, 0, stream>>>(qk, av);

    if (bx1) {
        // 4) x1b = bf16(x + a @ attn_proj_w^T + b)   (64x128: grid 6x196)
        gemm_bt<64, 128, true, 1, false, false><<<dim3(6, 196), 256, 0, stream>>>(
            av, wp, pb, x, x1b, MROWS, CH, NHEAD * TOPK);
        // 5) LN2: x1b (bf16) -> h2 (bf16)
        ln_k<false, false><<<MROWS, 256, 0, stream>>>(x1b, g2, bb2, hbuf);
        if (fullMLP) {
            // fc1: [12544 x 3072], K=768  (588 tiles on 256 blocks)
            gemm8p<CH, true, 0, true, false><<<256, 512, 0, stream>>>(
                hbuf, wf1, f1b, nullptr, gg, MROWS, HID);
            // fc2: [12544 x 768], K=3072 (147 tiles on 147 blocks)
            gemm8p<HID, true, 2, false, true><<<147, 512, 0, stream>>>(
                gg, wf2, f2bp, x1b, out, MROWS, CH);
        } else {
            for (int half = 0; half < 2; ++half) {
                const size_t ro = (size_t)half * MHALF;
                gemm_bt<128, 128, true, 0, true, false><<<dim3(24, 49), 256, 0, stream>>>(
                    hbuf + ro * CH, wf1, f1b, nullptr, gg, MHALF, HID, CH);
                gemm_bt<64, 256, true, 2, false, true><<<dim3(3, 98), 256, 0, stream>>>(
                    gg, wf2, f2bp, x1b + ro * CH, out + ro * CH, MHALF, CH, HID);
            }
        }
    } else {
        // conservative fallback: f32 x1 in d_out, halved MLP (74.7 MB ws)
        gemm_bt<64, 128, true, 1, false, true><<<dim3(6, 196), 256, 0, stream>>>(
            av, wp, pb, x, x1, MROWS, CH, NHEAD * TOPK);
        ln_k<true, false><<<MROWS, 256, 0, stream>>>(x1, g2, bb2, hbuf);
        for (int half = 0; half < 2; ++half) {
            const size_t ro = (size_t)half * MHALF;
            gemm_bt<128, 128, true, 0, true, false><<<dim3(24, 49), 256, 0, stream>>>(
                hbuf + ro * CH, wf1, f1b, nullptr, gg, MHALF, HID, CH);
            gemm_bt<64, 256, true, 1, false, true><<<dim3(3, 98), 256, 0, stream>>>(
                gg, wf2, f2bp, x1 + ro * CH, out + ro * CH, MHALF, CH, HID);
        }
    }
}

// Round 11
// 402.876 us; speedup vs baseline: 1.2143x; 1.0771x over previous
//
#include <hip/hip_runtime.h>

// Block_58394375356873: HomoAttention transformer block, MI355X gfx950.
// I/O dtype: float32 (per reference). Internal GEMM compute: bf16 MFMA.
// M = B*N = 64*196 = 12544.
//
// R11: GEMMs = R4-exact (best verified config; fp8 qk reverted — R10 showed
// gemm_f8 17us slower than bf16 despite half bytes: phases go latency-exposed).
// New: (1) prep_k merges weight-convert + LN1 into ONE dispatch (independent
// ops; ~10us/dispatch launch overhead documented); (2) attn_topk top-16 insert
// via v_med3_f32 sorted-insert identity: 16 VALU ops/value instead of 32.

#define BATCH 64
#define SEQ   196
#define CH    768
#define NHEAD 12
#define HDIM  64
#define TOPK  16
#define HID   3072
#define MROWS 12544
#define MHALF 6272
#define SCALE_F 0.125f  // 64^-0.5
#define NEGBIG -3e38f

typedef __bf16 bf16x8 __attribute__((ext_vector_type(8)));
typedef float  f32x4  __attribute__((ext_vector_type(4)));

__device__ __forceinline__ unsigned short f2b(float f) {
    union { float f; unsigned int i; } c; c.f = f;
    unsigned int u = c.i;
    return (unsigned short)((u + 0x7fffu + ((u >> 16) & 1u)) >> 16); // RNE
}
__device__ __forceinline__ float b2f(unsigned short u) {
    union { unsigned int i; float f; } c; c.i = ((unsigned int)u) << 16; return c.f;
}

// single-VALU median-of-3 (v_med3_f32; VOP3, all-VGPR operands)
__device__ __forceinline__ float med3(float a, float b, float c) {
    float r;
    asm("v_med3_f32 %0, %1, %2, %3" : "=v"(r) : "v"(a), "v"(b), "v"(c));
    return r;
}

// tanh-form GELU, |err vs exact erf-GELU| < 4e-4, ~10 VALU ops.
__device__ __forceinline__ float gelu_f(float v) {
    float u = v * (0.7978845608f + 0.0356774081f * v * v);
    float e = __expf(2.0f * u);
    float th = 1.0f - 2.0f / (e + 1.0f);
    return 0.5f * v * (1.0f + th);
}

// async global->LDS, 16B per lane. LDS base must be wave-uniform; HW adds lane*16.
__device__ __forceinline__ void async16(const unsigned short* g, unsigned short* l) {
    __builtin_amdgcn_global_load_lds(
        (const __attribute__((address_space(1))) unsigned int*)(g),
        (__attribute__((address_space(3))) unsigned int*)(l), 16, 0, 0);
}

// ---------------- prep: LN1 (blocks [0,MROWS)) + all-weights f32->bf16 (rest) -------
__global__ __launch_bounds__(256) void prep_k(const float* __restrict__ x,
                                              const float* __restrict__ gw,
                                              const float* __restrict__ bw,
                                              unsigned short* __restrict__ hbuf,
                                              const float* __restrict__ s0, unsigned short* __restrict__ d0, int n0,
                                              const float* __restrict__ s1, unsigned short* __restrict__ d1, int n1,
                                              const float* __restrict__ s2, unsigned short* __restrict__ d2, int n2,
                                              const float* __restrict__ s3, unsigned short* __restrict__ d3, int n3)
{
    const int bid = blockIdx.x;
    const int tid = threadIdx.x;
    __shared__ __align__(16) float red[8];
    if (bid < MROWS) {
        // ---- LN1: x(f32) row -> hbuf (bf16) ----
        const float* xr = x + (size_t)bid * CH;
        float v0 = xr[tid], v1 = xr[tid + 256], v2 = xr[tid + 512];
        float s  = v0 + v1 + v2;
        float sq = v0*v0 + v1*v1 + v2*v2;
#pragma unroll
        for (int off = 32; off > 0; off >>= 1) {
            s  += __shfl_down(s, off, 64);
            sq += __shfl_down(sq, off, 64);
        }
        if ((tid & 63) == 0) { red[(tid >> 6) * 2] = s; red[(tid >> 6) * 2 + 1] = sq; }
        __syncthreads();
        s  = red[0] + red[2] + red[4] + red[6];
        sq = red[1] + red[3] + red[5] + red[7];
        float mu  = s * (1.0f / CH);
        float var = sq * (1.0f / CH) - mu * mu;
        float rs  = rsqrtf(var + 1e-5f);
        unsigned short* orow = hbuf + (size_t)bid * CH;
        orow[tid]       = f2b((v0 - mu) * rs * gw[tid]       + bw[tid]);
        orow[tid + 256] = f2b((v1 - mu) * rs * gw[tid + 256] + bw[tid + 256]);
        orow[tid + 512] = f2b((v2 - mu) * rs * gw[tid + 512] + bw[tid + 512]);
    } else {
        // ---- weights f32 -> bf16 ----
        int idx = ((bid - MROWS) * 256 + tid) * 4;
        const float* s; unsigned short* d; int n;
        if (idx < n0) { s = s0; d = d0; n = n0; }
        else {
            idx -= n0;
            if (idx < n1) { s = s1; d = d1; n = n1; }
            else {
                idx -= n1;
                if (idx < n2) { s = s2; d = d2; n = n2; }
                else { idx -= n2; s = s3; d = d3; n = n3; }
            }
        }
        if (idx < n) {
            float4 v = *(const float4*)(s + idx);
            ushort4 o;
            o.x = f2b(v.x); o.y = f2b(v.y); o.z = f2b(v.z); o.w = f2b(v.w);
            *(ushort4*)(d + idx) = o;
        }
    }
}

// ---------------- LayerNorm: f32|bf16 in -> bf16 out, one block per row ----------------
template<bool INF32>
__global__ __launch_bounds__(256) void ln_k(const void* __restrict__ xin,
                                            const float* __restrict__ gw,
                                            const float* __restrict__ bw,
                                            unsigned short* __restrict__ out)
{
    const int row = blockIdx.x;
    const int tid = threadIdx.x;
    float v0, v1, v2;
    if constexpr (INF32) {
        const float* xr = (const float*)xin + (size_t)row * CH;
        v0 = xr[tid]; v1 = xr[tid + 256]; v2 = xr[tid + 512];
    } else {
        const unsigned short* xr = (const unsigned short*)xin + (size_t)row * CH;
        v0 = b2f(xr[tid]); v1 = b2f(xr[tid + 256]); v2 = b2f(xr[tid + 512]);
    }
    float s  = v0 + v1 + v2;
    float sq = v0*v0 + v1*v1 + v2*v2;
#pragma unroll
    for (int off = 32; off > 0; off >>= 1) {
        s  += __shfl_down(s, off, 64);
        sq += __shfl_down(sq, off, 64);
    }
    __shared__ __align__(16) float red[8];
    if ((tid & 63) == 0) { red[(tid >> 6) * 2] = s; red[(tid >> 6) * 2 + 1] = sq; }
    __syncthreads();
    s  = red[0] + red[2] + red[4] + red[6];
    sq = red[1] + red[3] + red[5] + red[7];
    float mu  = s * (1.0f / CH);
    float var = sq * (1.0f / CH) - mu * mu;
    float rs  = rsqrtf(var + 1e-5f);
    unsigned short* orow = out + (size_t)row * CH;
    orow[tid]       = f2b((v0 - mu) * rs * gw[tid]       + bw[tid]);
    orow[tid + 256] = f2b((v1 - mu) * rs * gw[tid + 256] + bw[tid + 256]);
    orow[tid + 512] = f2b((v2 - mu) * rs * gw[tid + 512] + bw[tid + 512]);
}

// ---------------- NT GEMM (legacy 2-barrier): C = A @ W^T (+bias)(+gelu)(+resid) ----
// Kept for attn-proj (K=192) and halved fallback paths (M=6272 not /256).
template<int TM, int TN, bool BIAS, int RES, bool GELU, bool OUTF>
__global__ __launch_bounds__(256, 4)
void gemm_bt(const unsigned short* __restrict__ A,
             const unsigned short* __restrict__ Bw,
             const float* __restrict__ bias,
             const void* __restrict__ resid,
             void* __restrict__ Cout,
             int M, int N, int K)
{
    constexpr int WROWS = (TM == 128) ? 2 : 1;
    constexpr int WCOLS = 4 / WROWS;
    constexpr int JF = TN / (16 * WCOLS);
    __shared__ __align__(16) unsigned short As[2][TM * 32];
    __shared__ __align__(16) unsigned short Bs[2][TN * 32];
    const int tid  = threadIdx.x;
    const int w    = tid >> 6;
    const int lane = tid & 63;

    const int gridN = gridDim.x, gridM = gridDim.y;
    const int lid = blockIdx.y * gridN + blockIdx.x;
    const int SG = 8 * gridN;
    const int sg = lid / SG, r = lid % SG;
    const int remM = gridM - sg * 8;
    int mloc, nloc;
    if (remM >= 8) { mloc = sg * 8 + (r & 7); nloc = r >> 3; }
    else           { mloc = sg * 8 + r % remM; nloc = r / remM; }
    const int tileM = mloc * TM;
    const int tileN = nloc * TN;

    const int wm = (w / WCOLS) * 64;
    const int wn = (w % WCOLS) * (JF * 16);
    const int q   = lane >> 4;
    const int l16 = lane & 15;
    const int csw = (q ^ (l16 & 3)) * 8;

    f32x4 acc[4][JF];
#pragma unroll
    for (int i = 0; i < 4; ++i)
#pragma unroll
        for (int j = 0; j < JF; ++j) acc[i][j] = (f32x4){0.f, 0.f, 0.f, 0.f};

    const int r0 = tid >> 2;
    const int g0 = ((tid & 3) ^ (r0 & 3)) * 8;

    const unsigned short* pB[TN / 64];
    const unsigned short* pA[TM / 64];
#pragma unroll
    for (int c = 0; c < TN / 64; ++c) pB[c] = Bw + (size_t)(tileN + r0 + c * 64) * K + g0;
#pragma unroll
    for (int c = 0; c < TM / 64; ++c) pA[c] = A + (size_t)(tileM + r0 + c * 64) * K + g0;

    auto stage = [&](int buf) {
#pragma unroll
        for (int c = 0; c < TN / 64; ++c) {
            async16(pB[c], &Bs[buf][(size_t)(c * 256 + w * 64) * 8]);
            pB[c] += 32;
        }
#pragma unroll
        for (int c = 0; c < TM / 64; ++c) {
            async16(pA[c], &As[buf][(size_t)(c * 256 + w * 64) * 8]);
            pA[c] += 32;
        }
    };

    const int kIters = K >> 5;
    stage(0);
    int cur = 0;
    for (int kt = 0; kt < kIters; ++kt) {
        __syncthreads();
        if (kt + 1 < kIters) stage(cur ^ 1);
        bf16x8 af[4], bfr[JF];
#pragma unroll
        for (int i = 0; i < 4; ++i)
            af[i] = *(const bf16x8*)&As[cur][(wm + i * 16 + l16) * 32 + csw];
#pragma unroll
        for (int j = 0; j < JF; ++j)
            bfr[j] = *(const bf16x8*)&Bs[cur][(wn + j * 16 + l16) * 32 + csw];
#pragma unroll
        for (int i = 0; i < 4; ++i)
#pragma unroll
            for (int j = 0; j < JF; ++j)
                acc[i][j] = __builtin_amdgcn_mfma_f32_16x16x32_bf16(af[i], bfr[j], acc[i][j], 0, 0, 0);
        cur ^= 1;
    }

#pragma unroll
    for (int i = 0; i < 4; ++i) {
#pragma unroll
        for (int r2 = 0; r2 < 4; ++r2) {
            int row = tileM + wm + i * 16 + q * 4 + r2;
#pragma unroll
            for (int j = 0; j < JF; ++j) {
                int col = tileN + wn + j * 16 + l16;
                float v = acc[i][j][r2];
                if (BIAS) v += bias[col];
                if (GELU) v = gelu_f(v);
                if (RES == 1) v += ((const float*)resid)[(size_t)row * N + col];
                if (RES == 2) v += b2f(((const unsigned short*)resid)[(size_t)row * N + col]);
                if (OUTF) ((float*)Cout)[(size_t)row * N + col] = v;
                else      ((unsigned short*)Cout)[(size_t)row * N + col] = f2b(v);
            }
        }
    }
}

// ---------------- Persistent 4-phase 256x256 NT GEMM (R4-exact, bf16) ----------------
template<int KC, bool BIAS, int RES, bool GELU, bool OUTF>
__global__ __launch_bounds__(512, 2)
void gemm8p(const unsigned short* __restrict__ A,
            const unsigned short* __restrict__ Bw,
            const float* __restrict__ bias,
            const void* __restrict__ resid,
            void* __restrict__ Cout,
            int M, int N)
{
    constexpr int T = KC / 64;
    static_assert((T & 1) == 0, "T must be even for persistent parity");
    __shared__ __align__(16) unsigned short As[2][256 * 64];
    __shared__ __align__(16) unsigned short Bs[2][256 * 64];
    const int tid  = threadIdx.x;
    const int w    = tid >> 6;
    const int lane = tid & 63;
    const int q    = lane >> 4;
    const int l16  = lane & 15;

    const int gridN = N >> 8, gridM = M >> 8;
    const int nt = gridN * gridM;
    const int P = gridDim.x;

    auto tileOf = [&](int lid2, int& tm, int& tn) {
        const int SG = 8 * gridN;
        const int sg = lid2 / SG, rr2 = lid2 % SG;
        const int remM = gridM - sg * 8;
        int mloc, nloc;
        if (remM >= 8) { mloc = sg * 8 + (rr2 & 7); nloc = rr2 >> 3; }
        else           { mloc = sg * 8 + rr2 % remM; nloc = rr2 / remM; }
        tm = mloc * 256; tn = nloc * 256;
    };

    const int wm = (w >> 2) * 128;
    const int wn = (w & 3) * 64;

    const int r0 = tid >> 3;
    const int g0 = (tid & 7) ^ (r0 & 7);
    const int rB = r0 + (r0 & 32);

    const int arow = wm + l16;
    const int brow = wn + l16;
    const int xsw  = l16 & 7;

    for (int t = (int)blockIdx.x; t < nt; t += P) {
        int tileM, tileN;
        tileOf(t, tileM, tileN);
        const bool hasNext = (t + P) < nt;
        int tileM2 = tileM, tileN2 = tileN;
        if (hasNext) tileOf(t + P, tileM2, tileN2);

        const unsigned short* pA0  = A  + (size_t)(tileM  + r0) * KC + g0 * 8;
        const unsigned short* pB0  = Bw + (size_t)(tileN  + rB) * KC + g0 * 8;
        const unsigned short* pA0n = A  + (size_t)(tileM2 + r0) * KC + g0 * 8;
        const unsigned short* pB0n = Bw + (size_t)(tileN2 + rB) * KC + g0 * 8;

        auto stageA = [&](int v, int j) {
            const unsigned short* base = (v == T) ? pA0n : pA0;
            const int vv = (v == T) ? 0 : v;
            const unsigned short* s = base + (size_t)(j * 64) * KC + vv * 64;
            unsigned short* d = As[vv & 1] + j * 4096 + w * 512;
            async16(s, d);
            async16(s + (size_t)128 * KC, d + 8192);
        };
        auto stageB = [&](int v, int j) {
            const unsigned short* base = (v == T) ? pB0n : pB0;
            const int vv = (v == T) ? 0 : v;
            const unsigned short* s = base + (size_t)(j * 32) * KC + vv * 64;
            unsigned short* d = Bs[vv & 1] + j * 2048 + (w * 8 + ((w & 4) << 3)) * 64;
            async16(s, d);
            async16(s + (size_t)128 * KC, d + 8192);
        };

        f32x4 acc[8][4];
#pragma unroll
        for (int i = 0; i < 8; ++i)
#pragma unroll
            for (int jn = 0; jn < 4; ++jn) acc[i][jn] = (f32x4){0.f, 0.f, 0.f, 0.f};

        if (t == (int)blockIdx.x) {
            stageA(0, 0); stageB(0, 0); stageB(0, 1); stageA(0, 1);
            asm volatile("s_waitcnt vmcnt(4)" ::: "memory");
            __builtin_amdgcn_s_barrier();
            asm volatile("" ::: "memory");
        }

#pragma unroll 2
        for (int u = 0; u < T; ++u) {
            const unsigned short* Ab = As[u & 1];
            const unsigned short* Bb = Bs[u & 1];
            const bool more = (u + 1 < T) || hasNext;
            bf16x8 af[4][2], b0[2][2], b1[2][2];

            // ---------- ph0 ----------
#pragma unroll
            for (int m = 0; m < 4; ++m)
#pragma unroll
                for (int kk = 0; kk < 2; ++kk)
                    af[m][kk] = *(const bf16x8*)&Ab[(arow + m * 16) * 64 + ((((kk << 2) | q) ^ xsw) << 3)];
#pragma unroll
            for (int n = 0; n < 2; ++n)
#pragma unroll
                for (int kk = 0; kk < 2; ++kk)
                    b0[n][kk] = *(const bf16x8*)&Bb[(brow + n * 16) * 64 + ((((kk << 2) | q) ^ xsw) << 3)];
            if (more) stageA(u + 1, 0);
            __builtin_amdgcn_s_setprio(1);
#pragma unroll
            for (int kk = 0; kk < 2; ++kk)
#pragma unroll
                for (int m = 0; m < 4; ++m)
#pragma unroll
                    for (int n = 0; n < 2; ++n)
                        acc[m][n] = __builtin_amdgcn_mfma_f32_16x16x32_bf16(af[m][kk], b0[n][kk], acc[m][n], 0, 0, 0);
            __builtin_amdgcn_s_setprio(0);

            // ---------- ph1 ----------
            if (more) asm volatile("s_waitcnt vmcnt(4)" ::: "memory");
            else      asm volatile("s_waitcnt vmcnt(2)" ::: "memory");
            __builtin_amdgcn_s_barrier();
            asm volatile("" ::: "memory");
#pragma unroll
            for (int n = 0; n < 2; ++n)
#pragma unroll
                for (int kk = 0; kk < 2; ++kk)
                    b1[n][kk] = *(const bf16x8*)&Bb[(brow + 32 + n * 16) * 64 + ((((kk << 2) | q) ^ xsw) << 3)];
            if (more) stageB(u + 1, 0);
            __builtin_amdgcn_s_setprio(1);
#pragma unroll
            for (int kk = 0; kk < 2; ++kk)
#pragma unroll
                for (int m = 0; m < 4; ++m)
#pragma unroll
                    for (int n = 0; n < 2; ++n)
                        acc[m][2 + n] = __builtin_amdgcn_mfma_f32_16x16x32_bf16(af[m][kk], b1[n][kk], acc[m][2 + n], 0, 0, 0);
            __builtin_amdgcn_s_setprio(0);

            // ---------- ph2 ----------
            if (more) asm volatile("s_waitcnt vmcnt(4)" ::: "memory");
            else      asm volatile("s_waitcnt vmcnt(0)" ::: "memory");
            __builtin_amdgcn_s_barrier();
            asm volatile("" ::: "memory");
#pragma unroll
            for (int m = 0; m < 4; ++m)
#pragma unroll
                for (int kk = 0; kk < 2; ++kk)
                    af[m][kk] = *(const bf16x8*)&Ab[(arow + 64 + m * 16) * 64 + ((((kk << 2) | q) ^ xsw) << 3)];
            if (more) stageB(u + 1, 1);
            __builtin_amdgcn_s_setprio(1);
#pragma unroll
            for (int kk = 0; kk < 2; ++kk)
#pragma unroll
                for (int m = 0; m < 4; ++m)
#pragma unroll
                    for (int n = 0; n < 2; ++n)
                        acc[4 + m][2 + n] = __builtin_amdgcn_mfma_f32_16x16x32_bf16(af[m][kk], b1[n][kk], acc[4 + m][2 + n], 0, 0, 0);
            __builtin_amdgcn_s_setprio(0);

            // ---------- ph3 ----------
            if (more) {
                stageA(u + 1, 1);
                asm volatile("s_waitcnt vmcnt(4)" ::: "memory");
                __builtin_amdgcn_s_barrier();
                asm volatile("" ::: "memory");
            }
            __builtin_amdgcn_s_setprio(1);
#pragma unroll
            for (int kk = 0; kk < 2; ++kk)
#pragma unroll
                for (int m = 0; m < 4; ++m)
#pragma unroll
                    for (int n = 0; n < 2; ++n)
                        acc[4 + m][n] = __builtin_amdgcn_mfma_f32_16x16x32_bf16(af[m][kk], b0[n][kk], acc[4 + m][n], 0, 0, 0);
            __builtin_amdgcn_s_setprio(0);
        }

        // ---------------- coalesced epilogue ----------------
        __syncthreads();

        float bshift[2][2];
        if (BIAS) {
#pragma unroll
            for (int nh = 0; nh < 2; ++nh)
#pragma unroll
                for (int n = 0; n < 2; ++n)
                    bshift[nh][n] = bias[tileN + wn + nh * 32 + n * 16 + l16];
        }

        if constexpr (!OUTF) {
            unsigned short* slab = &As[1][0] + (size_t)w * 1152;
            unsigned short* co = (unsigned short*)Cout;
#pragma unroll
            for (int mh = 0; mh < 2; ++mh)
#pragma unroll
                for (int m = 0; m < 4; ++m) {
#pragma unroll
                    for (int nh = 0; nh < 2; ++nh)
#pragma unroll
                        for (int n = 0; n < 2; ++n)
#pragma unroll
                            for (int r2 = 0; r2 < 4; ++r2) {
                                float v = acc[mh * 4 + m][nh * 2 + n][r2];
                                if (BIAS) v += bshift[nh][n];
                                if (GELU) v = gelu_f(v);
                                slab[(q * 4 + r2) * 72 + nh * 32 + n * 16 + l16] = f2b(v);
                            }
#pragma unroll
                    for (int h = 0; h < 2; ++h) {
                        const int lr = h * 8 + (lane >> 3);
                        const int grow = tileM + wm + mh * 64 + m * 16 + lr;
                        const int gcol = tileN + wn + (lane & 7) * 8;
                        uint4 pk = *(const uint4*)&slab[lr * 72 + (lane & 7) * 8];
                        if (RES != 0) {
                            unsigned short* ps = (unsigned short*)&pk;
#pragma unroll
                            for (int j = 0; j < 8; ++j) {
                                float v = b2f(ps[j]);
                                if (RES == 1) v += ((const float*)resid)[(size_t)grow * N + gcol + j];
                                if (RES == 2) v += b2f(((const unsigned short*)resid)[(size_t)grow * N + gcol + j]);
                                ps[j] = f2b(v);
                            }
                        }
                        *(uint4*)&co[(size_t)grow * N + gcol] = pk;
                    }
                }
        } else {
            float* slabf = (w == 7) ? (float*)&Bs[1][0]
                                    : (float*)&As[1][0] + (size_t)w * 1088;
            float* co = (float*)Cout;
#pragma unroll
            for (int mh = 0; mh < 2; ++mh)
#pragma unroll
                for (int m = 0; m < 4; ++m) {
#pragma unroll
                    for (int nh = 0; nh < 2; ++nh)
#pragma unroll
                        for (int n = 0; n < 2; ++n)
#pragma unroll
                            for (int r2 = 0; r2 < 4; ++r2) {
                                float v = acc[mh * 4 + m][nh * 2 + n][r2];
                                if (BIAS) v += bshift[nh][n];
                                if (GELU) v = gelu_f(v);
                                slabf[(q * 4 + r2) * 68 + nh * 32 + n * 16 + l16] = v;
                            }
#pragma unroll
                    for (int i4 = 0; i4 < 4; ++i4) {
                        const int lr = i4 * 4 + (lane >> 4);
                        const int grow = tileM + wm + mh * 64 + m * 16 + lr;
                        const int gcol = tileN + wn + (lane & 15) * 4;
                        f32x4 vv = *(const f32x4*)&slabf[lr * 68 + (lane & 15) * 4];
                        if (RES == 1) {
                            const float4 r4 = *(const float4*)&((const float*)resid)[(size_t)grow * N + gcol];
                            vv[0] += r4.x; vv[1] += r4.y; vv[2] += r4.z; vv[3] += r4.w;
                        }
                        if (RES == 2) {
                            const ushort4 r4 = *(const ushort4*)&((const unsigned short*)resid)[(size_t)grow * N + gcol];
                            vv[0] += b2f(r4.x); vv[1] += b2f(r4.y); vv[2] += b2f(r4.z); vv[3] += b2f(r4.w);
                        }
                        *(f32x4*)&co[(size_t)grow * N + gcol] = vv;
                    }
                }
        }

        if (hasNext) {
            asm volatile("s_waitcnt vmcnt(4)" ::: "memory");
            __syncthreads();
        }
    }
}

// ---------------- Attention: MFMA scores + in-register top-16 + softmax ----------------
// Top-16 insert via sorted-insert identity: t[j] = med3(v, t[j], t[j-1]) for
// j=15..1 (in place, descending), then t[0] = max(t[0], v). 16 VALU ops/value.
__global__ __launch_bounds__(256) void attn_topk(const unsigned short* __restrict__ qk,
                                                 unsigned short* __restrict__ aout)
{
    const int bh = blockIdx.x;
    const int b = bh / NHEAD, h = bh % NHEAD;
    __shared__ __align__(16) unsigned short Qs[208 * 64];
    __shared__ __align__(16) unsigned short Ks[208 * 64];
    const int tid = threadIdx.x;

    for (int i = tid; i < 208 * 8; i += 256) {
        int row = i >> 3, c = i & 7;
        uint4 vq = make_uint4(0, 0, 0, 0), vk = vq;
        if (row < SEQ) {
            const uint4* gp = (const uint4*)(qk + ((size_t)(b * SEQ + row) * 1536 + h * 64));
            vq = gp[c];        // q half
            vk = gp[c + 96];   // k half: +768 shorts = +96 uint4
        }
        int slot = c ^ (row & 7);
        *(uint4*)&Qs[row * 64 + slot * 8] = vq;
        *(uint4*)&Ks[row * 64 + slot * 8] = vk;
    }
    __syncthreads();

    const int w = tid >> 6, lane = tid & 63;
    const int q = lane >> 4, l16 = lane & 15;

    for (int tn = w; tn < 13; tn += 4) {
        const int nrow = tn * 16 + l16;
        const int nsw = nrow & 7;
        bf16x8 bq0 = *(const bf16x8*)&Qs[nrow * 64 + ((0 * 4 + q) ^ nsw) * 8];
        bf16x8 bq1 = *(const bf16x8*)&Qs[nrow * 64 + ((1 * 4 + q) ^ nsw) * 8];

        float t[TOPK];
#pragma unroll
        for (int j = 0; j < TOPK; ++j) t[j] = NEGBIG;

        for (int tm = 0; tm < 12; ++tm) {
            const int mrow = tm * 16 + l16;
            const int msw = mrow & 7;
            bf16x8 ak0 = *(const bf16x8*)&Ks[mrow * 64 + ((0 * 4 + q) ^ msw) * 8];
            bf16x8 ak1 = *(const bf16x8*)&Ks[mrow * 64 + ((1 * 4 + q) ^ msw) * 8];
            f32x4 acc = (f32x4){0.f, 0.f, 0.f, 0.f};
            acc = __builtin_amdgcn_mfma_f32_16x16x32_bf16(ak0, bq0, acc, 0, 0, 0);
            acc = __builtin_amdgcn_mfma_f32_16x16x32_bf16(ak1, bq1, acc, 0, 0, 0);
#pragma unroll
            for (int r = 0; r < 4; ++r) {
                float v = acc[r];
#pragma unroll
                for (int j = TOPK - 1; j >= 1; --j)
                    t[j] = med3(v, t[j], t[j - 1]);
                t[0] = fmaxf(t[0], v);
            }
        }
        {   // m-tile 12: m = 192 + q*4 + r valid only for q==0
            const int mrow = 12 * 16 + l16;
            const int msw = mrow & 7;
            bf16x8 ak0 = *(const bf16x8*)&Ks[mrow * 64 + ((0 * 4 + q) ^ msw) * 8];
            bf16x8 ak1 = *(const bf16x8*)&Ks[mrow * 64 + ((1 * 4 + q) ^ msw) * 8];
            f32x4 acc = (f32x4){0.f, 0.f, 0.f, 0.f};
            acc = __builtin_amdgcn_mfma_f32_16x16x32_bf16(ak0, bq0, acc, 0, 0, 0);
            acc = __builtin_amdgcn_mfma_f32_16x16x32_bf16(ak1, bq1, acc, 0, 0, 0);
#pragma unroll
            for (int r = 0; r < 4; ++r) {
                float v = (q == 0) ? acc[r] : NEGBIG;
#pragma unroll
                for (int j = TOPK - 1; j >= 1; --j)
                    t[j] = med3(v, t[j], t[j - 1]);
                t[0] = fmaxf(t[0], v);
            }
        }

#pragma unroll
        for (int stage = 0; stage < 2; ++stage) {
            const int xm = 16 << stage;
            float bl[TOPK], c[TOPK];
#pragma unroll
            for (int j = 0; j < TOPK; ++j) bl[j] = __shfl_xor(t[j], xm, 64);
#pragma unroll
            for (int j = 0; j < TOPK; ++j) c[j] = fmaxf(t[j], bl[TOPK - 1 - j]);
#pragma unroll
            for (int s = 8; s >= 1; s >>= 1) {
#pragma unroll
                for (int i = 0; i < TOPK; ++i) {
                    if ((i & s) == 0) {
                        float mx = fmaxf(c[i], c[i + s]);
                        c[i + s] = fminf(c[i], c[i + s]);
                        c[i] = mx;
                    }
                }
            }
#pragma unroll
            for (int j = 0; j < TOPK; ++j) t[j] = c[j];
        }

        if (q == 0 && nrow < SEQ) {
            float e[TOPK], sum = 0.f;
#pragma unroll
            for (int j = 0; j < TOPK; ++j) { e[j] = __expf((t[j] - t[0]) * SCALE_F); sum += e[j]; }
            float inv = 1.0f / sum;
            unsigned int pk[8];
#pragma unroll
            for (int jj = 0; jj < 8; ++jj)
                pk[jj] = (unsigned int)f2b(e[2 * jj] * inv) |
                         ((unsigned int)f2b(e[2 * jj + 1] * inv) << 16);
            unsigned short* dst = aout + ((size_t)(b * SEQ + nrow)) * (NHEAD * TOPK) + h * TOPK;
            ((uint4*)dst)[0] = make_uint4(pk[0], pk[1], pk[2], pk[3]);
            ((uint4*)dst)[1] = make_uint4(pk[4], pk[5], pk[6], pk[7]);
        }
    }
}

// ---------------- Launch ----------------
extern "C" void kernel_launch(void* const* d_in, const int* in_sizes, int n_in,
                              void* d_out, int out_size, void* d_ws, size_t ws_size,
                              hipStream_t stream)
{
    const float* x    = (const float*)d_in[0];
    const float* g1   = (const float*)d_in[1];
    const float* bb1  = (const float*)d_in[2];
    const float* qkw  = (const float*)d_in[3];
    const float* pw   = (const float*)d_in[4];
    const float* pb   = (const float*)d_in[5];
    const float* g2   = (const float*)d_in[6];
    const float* bb2  = (const float*)d_in[7];
    const float* f1w  = (const float*)d_in[8];
    const float* f1b  = (const float*)d_in[9];
    const float* f2w  = (const float*)d_in[10];
    const float* f2bp = (const float*)d_in[11];
    float* out = (float*)d_out;

    // layout: hbuf | weights(wqk,wp,wf1,wf2) | av | qk/gg | x1b
    char* ws = (char*)d_ws;
    const size_t SZ_H   = (size_t)MROWS * CH * 2;              // 19,267,584
    const size_t N_WQK  = (size_t)2 * CH * CH;
    const size_t N_WP   = (size_t)CH * (NHEAD * TOPK);
    const size_t N_WF   = (size_t)HID * CH;
    const size_t SZ_W   = (N_WQK + N_WP + 2 * N_WF) * 2;       // 12,091,392
    const size_t SZ_A   = (size_t)MROWS * (NHEAD * TOPK) * 2;  //  4,816,896
    const size_t SZ_QK  = (size_t)MROWS * 2 * CH * 2;          // 38,535,168
    const size_t SZ_GGF = (size_t)MROWS * HID * 2;             // 77,070,336

    unsigned short* hbuf = (unsigned short*)(ws);
    unsigned short* wqk  = (unsigned short*)(ws + SZ_H);
    unsigned short* wp   = wqk + N_WQK;
    unsigned short* wf1  = wp  + N_WP;
    unsigned short* wf2  = wf1 + N_WF;
    unsigned short* av   = (unsigned short*)(ws + SZ_H + SZ_W);
    unsigned short* qk   = (unsigned short*)(ws + SZ_H + SZ_W + SZ_A);
    unsigned short* gg   = qk;   // overlays qk (dead by MLP time)

    const size_t base = SZ_H + SZ_W + SZ_A;
    const bool fullMLP = ws_size >= base + SZ_GGF + SZ_H;      // 132.5 MB: full-M + bf16 x1
    const bool bx1     = fullMLP || ws_size >= base + SZ_QK + SZ_H;  // 94 MB: halves + bf16 x1
    unsigned short* x1b = (unsigned short*)(ws + base + (fullMLP ? SZ_GGF : SZ_QK));
    float* x1 = out;   // f32 fallback residual lives in d_out

    // 0+1) merged: LN1 (x f32 -> hbuf bf16) + all weights f32 -> bf16
    {
        int total4 = (int)((N_WQK + N_WP + 2 * N_WF) / 4);            // 1,511,424
        int wblk   = (total4 + 255) / 256;                            // 5,904
        prep_k<<<MROWS + wblk, 256, 0, stream>>>(
            x, g1, bb1, hbuf,
            qkw, wqk, (int)N_WQK, pw, wp, (int)N_WP,
            f1w, wf1, (int)N_WF, f2w, wf2, (int)N_WF);
    }

    // 2) qk = h @ qk_w^T   [12544 x 1536], K=768   (persistent: 294 tiles on 256 blocks)
    gemm8p<CH, false, 0, false, false><<<256, 512, 0, stream>>>(
        hbuf, wqk, nullptr, nullptr, qk, MROWS, 2 * CH);
    // 3) attention -> top16 softmax weights [12544 x 192] bf16
    attn_topk<<<BATCH * NHEAD, 256, 0, stream>>>(qk, av);

    if (bx1) {
        // 4) x1b = bf16(x + a @ attn_proj_w^T + b)   (64x128: grid 6x196)
        gemm_bt<64, 128, true, 1, false, false><<<dim3(6, 196), 256, 0, stream>>>(
            av, wp, pb, x, x1b, MROWS, CH, NHEAD * TOPK);
        // 5) LN2: x1b (bf16) -> h2
        ln_k<false><<<MROWS, 256, 0, stream>>>(x1b, g2, bb2, hbuf);
        if (fullMLP) {
            // fc1: [12544 x 3072], K=768  (588 tiles on 256 blocks)
            gemm8p<CH, true, 0, true, false><<<256, 512, 0, stream>>>(
                hbuf, wf1, f1b, nullptr, gg, MROWS, HID);
            // fc2: [12544 x 768], K=3072 (147 tiles on 147 blocks)
            gemm8p<HID, true, 2, false, true><<<147, 512, 0, stream>>>(
                gg, wf2, f2bp, x1b, out, MROWS, CH);
        } else {
            for (int half = 0; half < 2; ++half) {
                const size_t ro = (size_t)half * MHALF;
                gemm_bt<128, 128, true, 0, true, false><<<dim3(24, 49), 256, 0, stream>>>(
                    hbuf + ro * CH, wf1, f1b, nullptr, gg, MHALF, HID, CH);
                gemm_bt<64, 256, true, 2, false, true><<<dim3(3, 98), 256, 0, stream>>>(
                    gg, wf2, f2bp, x1b + ro * CH, out + ro * CH, MHALF, CH, HID);
            }
        }
    } else {
        // conservative fallback: f32 x1 in d_out, halved MLP (74.7 MB ws)
        gemm_bt<64, 128, true, 1, false, true><<<dim3(6, 196), 256, 0, stream>>>(
            av, wp, pb, x, x1, MROWS, CH, NHEAD * TOPK);
        ln_k<true><<<MROWS, 256, 0, stream>>>(x1, g2, bb2, hbuf);
        for (int half = 0; half < 2; ++half) {
            const size_t ro = (size_t)half * MHALF;
            gemm_bt<128, 128, true, 0, true, false><<<dim3(24, 49), 256, 0, stream>>>(
                hbuf + ro * CH, wf1, f1b, nullptr, gg, MHALF, HID, CH);
            gemm_bt<64, 256, true, 1, false, true><<<dim3(3, 98), 256, 0, stream>>>(
                gg, wf2, f2bp, x1 + ro * CH, out + ro * CH, MHALF, CH, HID);
        }
    }
}